// Round 5
// baseline (1650.058 us; speedup 1.0000x reference)
//
#include <hip/hip_runtime.h>
#include <hip/hip_bf16.h>

#define Vn 10000
#define En 300
#define Hn 256
#define Gn 1024   // 4*H
#define Ln 9
#define Bn 128
#define Tn 512

static __device__ __forceinline__ float bf2f(unsigned short u) {
    return __uint_as_float(((unsigned int)u) << 16);
}
static __device__ __forceinline__ unsigned short f2bf(float f) {
    unsigned int x = __float_as_uint(f);
    return (unsigned short)((x + 0x7FFFu + ((x >> 16) & 1u)) >> 16);
}
static __device__ __forceinline__ float sigm(float x) {
    return 1.f / (1.f + __expf(-x));
}
static __device__ __forceinline__ float tanh_fast(float x) {
    return 2.f / (1.f + __expf(-2.f * x)) - 1.f;
}
static __device__ __forceinline__ int dot4(unsigned int w, int h, int acc) {
    return __builtin_amdgcn_sdot4((int)w, h, acc, false);
}

// ---- transpose Wih (1024,300) -> WihT (300,1024), f32 ----
__global__ __launch_bounds__(256) void k_transpose_wih(
    const float* __restrict__ Wf, const float* __restrict__ Wb,
    float* __restrict__ Tf, float* __restrict__ Tb) {
    int n = blockIdx.x * 256 + threadIdx.x;          // < 307200
    const float* src = blockIdx.y ? Wb : Wf;
    float* dst = blockIdx.y ? Tb : Tf;
    int e = n / Gn, j = n % Gn;
    dst[n] = src[j * En + e];
}

// ---- quantize Whh (1024,256) f32 -> i8, per-gate-row scale ----
// Layout: dword d (k=4d..4d+3) of row j at uint index ((d>>2)*1024 + j)*4 + (d&3)
// i.e. uint4 tiles [d4][1024]; k_lstm thread j reads tiles at d4*1024 + j.
__global__ __launch_bounds__(64) void k_quant_whh(
    const float* __restrict__ Wf, const float* __restrict__ Wb,
    unsigned int* __restrict__ q_f, unsigned int* __restrict__ q_b,
    float* __restrict__ scl_f, float* __restrict__ scl_b) {
    int j = blockIdx.x;                 // 0..1023 (gate-row)
    int dir = blockIdx.y;
    int lane = threadIdx.x;             // 0..63 = dword index d
    const float* W = dir ? Wb : Wf;
    unsigned int* dst = dir ? q_b : q_f;
    float4 w = *(const float4*)&W[(size_t)j * Hn + 4 * lane];
    float m = fmaxf(fmaxf(fabsf(w.x), fabsf(w.y)), fmaxf(fabsf(w.z), fabsf(w.w)));
    #pragma unroll
    for (int sft = 32; sft >= 1; sft >>= 1) m = fmaxf(m, __shfl_xor(m, sft, 64));
    float inv = (m > 0.f) ? (127.f / m) : 0.f;
    int q0 = (int)rintf(w.x * inv), q1 = (int)rintf(w.y * inv);
    int q2 = (int)rintf(w.z * inv), q3 = (int)rintf(w.w * inv);
    unsigned int d = (q0 & 255) | ((q1 & 255) << 8) | ((q2 & 255) << 16) | ((q3 & 255) << 24);
    dst[(size_t)((lane >> 2) * 1024 + j) * 4 + (lane & 3)] = d;
    if (lane == 0) (dir ? scl_b : scl_f)[j] = m / 16129.f;
}

// ---- P = emb @ WihT + b : (10000, 1024) bf16 per direction ----
__global__ __launch_bounds__(256) void k_proj(
    const float* __restrict__ emb,
    const float* __restrict__ WihT_f, const float* __restrict__ WihT_b,
    const float* __restrict__ b_f, const float* __restrict__ b_b,
    unsigned short* __restrict__ Pf, unsigned short* __restrict__ Pb) {
    int tid = threadIdx.x;
    int tx = tid & 63, ty = tid >> 6;
    int dir = blockIdx.z;
    const float* WT = dir ? WihT_b : WihT_f;
    const float* bias = dir ? b_b : b_f;
    unsigned short* P = dir ? Pb : Pf;
    int v0 = blockIdx.x * 16 + ty * 4;               // 625*16 = 10000 exact
    int j0 = blockIdx.y * 256 + tx * 4;
    float4 acc0 = {0,0,0,0}, acc1 = {0,0,0,0}, acc2 = {0,0,0,0}, acc3 = {0,0,0,0};
    for (int e0 = 0; e0 < En; e0 += 4) {             // 300 = 75*4 exact
        float4 a0 = *(const float4*)&emb[(size_t)(v0 + 0) * En + e0];
        float4 a1 = *(const float4*)&emb[(size_t)(v0 + 1) * En + e0];
        float4 a2 = *(const float4*)&emb[(size_t)(v0 + 2) * En + e0];
        float4 a3 = *(const float4*)&emb[(size_t)(v0 + 3) * En + e0];
        float4 w0 = *(const float4*)&WT[(size_t)(e0 + 0) * Gn + j0];
        float4 w1 = *(const float4*)&WT[(size_t)(e0 + 1) * Gn + j0];
        float4 w2 = *(const float4*)&WT[(size_t)(e0 + 2) * Gn + j0];
        float4 w3 = *(const float4*)&WT[(size_t)(e0 + 3) * Gn + j0];
        acc0.x += a0.x*w0.x + a0.y*w1.x + a0.z*w2.x + a0.w*w3.x;
        acc0.y += a0.x*w0.y + a0.y*w1.y + a0.z*w2.y + a0.w*w3.y;
        acc0.z += a0.x*w0.z + a0.y*w1.z + a0.z*w2.z + a0.w*w3.z;
        acc0.w += a0.x*w0.w + a0.y*w1.w + a0.z*w2.w + a0.w*w3.w;
        acc1.x += a1.x*w0.x + a1.y*w1.x + a1.z*w2.x + a1.w*w3.x;
        acc1.y += a1.x*w0.y + a1.y*w1.y + a1.z*w2.y + a1.w*w3.y;
        acc1.z += a1.x*w0.z + a1.y*w1.z + a1.z*w2.z + a1.w*w3.z;
        acc1.w += a1.x*w0.w + a1.y*w1.w + a1.z*w2.w + a1.w*w3.w;
        acc2.x += a2.x*w0.x + a2.y*w1.x + a2.z*w2.x + a2.w*w3.x;
        acc2.y += a2.x*w0.y + a2.y*w1.y + a2.z*w2.y + a2.w*w3.y;
        acc2.z += a2.x*w0.z + a2.y*w1.z + a2.z*w2.z + a2.w*w3.z;
        acc2.w += a2.x*w0.w + a2.y*w1.w + a2.z*w2.w + a2.w*w3.w;
        acc3.x += a3.x*w0.x + a3.y*w1.x + a3.z*w2.x + a3.w*w3.x;
        acc3.y += a3.x*w0.y + a3.y*w1.y + a3.z*w2.y + a3.w*w3.y;
        acc3.z += a3.x*w0.z + a3.y*w1.z + a3.z*w2.z + a3.w*w3.z;
        acc3.w += a3.x*w0.w + a3.y*w1.w + a3.z*w2.w + a3.w*w3.w;
    }
    float4 bb = *(const float4*)&bias[j0];
    float4 av[4] = {acc0, acc1, acc2, acc3};
    #pragma unroll
    for (int r = 0; r < 4; ++r) {
        ushort4 o;
        o.x = f2bf(av[r].x + bb.x); o.y = f2bf(av[r].y + bb.y);
        o.z = f2bf(av[r].z + bb.z); o.w = f2bf(av[r].w + bb.w);
        *(ushort4*)&P[(size_t)(v0 + r) * Gn + j0] = o;
    }
}

// ---- persistent BiLSTM recurrence: 256 WGs = 2 dir x 128 batch, 512 thr ----
// Thread j owns gate-rows {j, j+512}: weights resident in 32 uint4 = 128 VGPR
// (launch_bounds(512,2) -> cap 256, no remat). h-broadcast: ONE ds_read_b128
// per wave, then v_readlane -> SGPR operand of v_dot4 (DS insts/step: 256->~10).
// Emissions fused (waves 4..7).
__global__ __launch_bounds__(512, 2) void k_lstm(
    const int* __restrict__ ids,
    const uint4* __restrict__ q_f, const uint4* __restrict__ q_b,
    const float* __restrict__ scl_f, const float* __restrict__ scl_b,
    const unsigned short* __restrict__ Pf, const unsigned short* __restrict__ Pb,
    const float* __restrict__ Wc,
    float* __restrict__ em_pf, float* __restrict__ em_pb) {
    __shared__ float g_stage[Gn];            // 4 KB gate preacts
    __shared__ float hstage[Hn];             // 1 KB f32 h for emission dot
    __shared__ uint4 h8v[16];                // 256 B i8 h (dword d = units 4d..4d+3)
    __shared__ int ids_lds[Tn];              // 2 KB
    __shared__ float wc_lds[Ln][Hn];         // 9 KB this dir's half of Wc
    int tid = threadIdx.x;
    int dir = blockIdx.x >> 7;
    int batch = blockIdx.x & 127;
    const uint4* q = dir ? q_b : q_f;
    const unsigned short* P = dir ? Pb : Pf;
    float* em_p = dir ? em_pb : em_pf;

    uint4 wA[16], wB[16];
    #pragma unroll
    for (int d4 = 0; d4 < 16; ++d4) {
        wA[d4] = q[(size_t)d4 * 1024 + tid];
        wB[d4] = q[(size_t)d4 * 1024 + tid + 512];
    }
    const float* scl = dir ? scl_b : scl_f;
    float sc0 = scl[tid], sc1 = scl[tid + 512];
    ids_lds[tid] = ids[batch * Tn + tid];                 // Tn == 512 exactly
    for (int i = tid; i < Ln * Hn; i += 512)
        wc_lds[i >> 8][i & 255] = Wc[(size_t)(i >> 8) * 512 + dir * 256 + (i & 255)];
    if (tid < 16) { uint4 z = {0u, 0u, 0u, 0u}; h8v[tid] = z; }
    float c = 0.f;
    __syncthreads();

    int t0 = dir ? (Tn - 1) : 0;
    float p0 = bf2f(P[(size_t)ids_lds[t0] * Gn + tid]);
    float p1 = bf2f(P[(size_t)ids_lds[t0] * Gn + tid + 512]);

    for (int s = 0; s < Tn; ++s) {
        int t = dir ? (Tn - 1 - s) : s;
        int s2 = (s + 1 < Tn) ? s + 1 : Tn - 1;
        int t2 = dir ? (Tn - 1 - s2) : s2;
        const unsigned short* pr = P + (size_t)ids_lds[t2] * Gn;
        unsigned short n0 = pr[tid], n1 = pr[tid + 512]; // next-step prefetch

        uint4 hv = h8v[tid & 15];                        // ONE ds_read_b128/wave
        int accA = 0, accB = 0;
        #pragma unroll
        for (int d4 = 0; d4 < 16; ++d4) {
            int hX = __builtin_amdgcn_readlane((int)hv.x, d4);
            int hY = __builtin_amdgcn_readlane((int)hv.y, d4);
            int hZ = __builtin_amdgcn_readlane((int)hv.z, d4);
            int hW = __builtin_amdgcn_readlane((int)hv.w, d4);
            accA = dot4(wA[d4].x, hX, accA);
            accA = dot4(wA[d4].y, hY, accA);
            accA = dot4(wA[d4].z, hZ, accA);
            accA = dot4(wA[d4].w, hW, accA);
            accB = dot4(wB[d4].x, hX, accB);
            accB = dot4(wB[d4].y, hY, accB);
            accB = dot4(wB[d4].z, hZ, accB);
            accB = dot4(wB[d4].w, hW, accB);
        }
        g_stage[tid]       = sc0 * (float)accA + p0;
        g_stage[tid + 512] = sc1 * (float)accB + p1;
        __syncthreads();                                 // B1: gates ready
        if (tid < Hn) {
            float gi = g_stage[tid];
            float gf = g_stage[tid + 256];
            float gg = g_stage[tid + 512];
            float go = g_stage[tid + 768];
            float cn = sigm(gf) * c + sigm(gi) * tanh_fast(gg);
            float hn = sigm(go) * tanh_fast(cn);
            c = cn;
            hstage[tid] = hn;
            ((char*)h8v)[tid] = (char)(int)rintf(127.f * hn);
        }
        __syncthreads();                                 // B2: new h visible
        if (tid >= 256) {                                // waves 4..7: emissions
            int wv = (tid >> 6) - 4;                     // 0..3
            int lane = tid & 63;
            int l1 = (wv == 3) ? 9 : 2 * wv + 2;
            for (int l = 2 * wv; l < l1; ++l) {
                float4 h4 = *(const float4*)&hstage[lane * 4];
                float4 w4 = *(const float4*)&wc_lds[l][lane * 4];
                float p = h4.x * w4.x + h4.y * w4.y + h4.z * w4.z + h4.w * w4.w;
                #pragma unroll
                for (int m = 32; m >= 1; m >>= 1) p += __shfl_xor(p, m, 64);
                if (lane == 0) em_p[((size_t)t * Bn + batch) * Ln + l] = p;
            }
        }
        p0 = bf2f(n0); p1 = bf2f(n1);
    }
}

// ---- CRF denominator: 128 single-wave WGs, shuffle-based, barrier-free ----
// alpha for label j lives in lane j (j<9). alpha_i broadcasts via __shfl.
__global__ __launch_bounds__(64) void k_crf_den(
    const float* __restrict__ pf, const float* __restrict__ pb,
    const float* __restrict__ bc, const int* __restrict__ mask,
    const float* __restrict__ trans, const float* __restrict__ start,
    const float* __restrict__ endt, float* __restrict__ logZ) {
    int b = blockIdx.x, j = threadIdx.x;
    int jj = (j < Ln) ? j : Ln - 1;                  // clamp for safe loads
    float trj[Ln];
    #pragma unroll
    for (int i = 0; i < Ln; ++i) trj[i] = trans[i * Ln + jj];
    float bcj = bc[jj];
    size_t ix0 = (size_t)b * Ln + jj;
    float alpha = start[jj] + pf[ix0] + pb[ix0] + bcj;
    // software pipeline depth 2 on emissions + mask
    size_t ix1 = (size_t)(1 * Bn + b) * Ln + jj;
    size_t ix2 = (size_t)(2 * Bn + b) * Ln + jj;
    float e1 = pf[ix1] + pb[ix1] + bcj;
    float e2 = pf[ix2] + pb[ix2] + bcj;
    int m1 = mask[b * Tn + 1];
    int m2 = mask[b * Tn + 2];
    for (int t = 1; t < Tn; ++t) {
        float s0 = __shfl(alpha, 0, 64) + trj[0];
        float s1 = __shfl(alpha, 1, 64) + trj[1];
        float s2 = __shfl(alpha, 2, 64) + trj[2];
        float s3 = __shfl(alpha, 3, 64) + trj[3];
        float s4 = __shfl(alpha, 4, 64) + trj[4];
        float s5 = __shfl(alpha, 5, 64) + trj[5];
        float s6 = __shfl(alpha, 6, 64) + trj[6];
        float s7 = __shfl(alpha, 7, 64) + trj[7];
        float s8 = __shfl(alpha, 8, 64) + trj[8];
        float mx = fmaxf(fmaxf(fmaxf(s0, s1), fmaxf(s2, s3)),
                         fmaxf(fmaxf(s4, s5), fmaxf(fmaxf(s6, s7), s8)));
        float sum = __expf(s0 - mx) + __expf(s1 - mx) + __expf(s2 - mx)
                  + __expf(s3 - mx) + __expf(s4 - mx) + __expf(s5 - mx)
                  + __expf(s6 - mx) + __expf(s7 - mx) + __expf(s8 - mx);
        float nxt = mx + __logf(sum) + e1;
        if (m1) alpha = nxt;
        e1 = e2; m1 = m2;
        int t2 = (t + 2 < Tn) ? t + 2 : Tn - 1;
        size_t ixn = (size_t)(t2 * Bn + b) * Ln + jj;
        e2 = pf[ixn] + pb[ixn] + bcj;
        m2 = mask[b * Tn + t2];
    }
    float s = (j < Ln) ? alpha + endt[j] : -1e30f;
    float mx = s;
    #pragma unroll
    for (int d = 32; d >= 1; d >>= 1) mx = fmaxf(mx, __shfl_xor(mx, d, 64));
    float sm = __expf(s - mx);
    #pragma unroll
    for (int d = 32; d >= 1; d >>= 1) sm += __shfl_xor(sm, d, 64);
    if (j == 0) logZ[b] = mx + __logf(sm);
}

// ---- CRF numerator: gold-path score is a plain sum -> fully parallel over t ----
__global__ __launch_bounds__(64) void k_crf_num(
    const float* __restrict__ pf, const float* __restrict__ pb,
    const float* __restrict__ bc, const int* __restrict__ labels,
    const int* __restrict__ mask, const float* __restrict__ trans,
    const float* __restrict__ start, const float* __restrict__ endt,
    float* __restrict__ score) {
    int b = blockIdx.x, lane = threadIdx.x;
    float acc = 0.f; int cnt = 0;
    for (int t = lane; t < Tn; t += 64) {
        int tag = labels[b * Tn + t];
        int mt = mask[b * Tn + t];
        cnt += mt;
        size_t ix = (size_t)(t * Bn + b) * Ln + tag;
        float e = pf[ix] + pb[ix] + bc[tag];
        if (t == 0) {
            acc += start[tag] + e;
        } else {
            int prev = labels[b * Tn + t - 1];
            if (mt) acc += trans[prev * Ln + tag] + e;
        }
    }
    #pragma unroll
    for (int m = 32; m >= 1; m >>= 1) {
        acc += __shfl_xor(acc, m, 64);
        cnt += __shfl_xor(cnt, m, 64);
    }
    if (lane == 0) {
        int send = cnt - 1;
        int last = labels[b * Tn + send];
        score[b] = acc + endt[last];
    }
}

__global__ __launch_bounds__(128) void k_final(
    const float* __restrict__ score, const float* __restrict__ logZ,
    float* __restrict__ out) {
    __shared__ float s_s[128];
    int tid = threadIdx.x;
    s_s[tid] = score[tid] - logZ[tid];
    #pragma unroll
    for (int m = 64; m >= 1; m >>= 1) {
        __syncthreads();
        if (tid < m) s_s[tid] += s_s[tid + m];
    }
    if (tid == 0) out[0] = -s_s[0] / (float)Bn;
}

extern "C" void kernel_launch(void* const* d_in, const int* in_sizes, int n_in,
                              void* d_out, int out_size, void* d_ws, size_t ws_size,
                              hipStream_t stream) {
    const int* ids = (const int*)d_in[0];
    const int* msk = (const int*)d_in[1];
    const int* lbl = (const int*)d_in[2];
    const float* emb = (const float*)d_in[3];
    const float* Wih_f = (const float*)d_in[4];
    const float* Whh_f = (const float*)d_in[5];
    const float* b_f = (const float*)d_in[6];
    const float* Wih_b = (const float*)d_in[7];
    const float* Whh_b = (const float*)d_in[8];
    const float* b_b = (const float*)d_in[9];
    const float* Wc = (const float*)d_in[10];
    const float* bc = (const float*)d_in[11];
    const float* trans = (const float*)d_in[12];
    const float* st = (const float*)d_in[13];
    const float* en = (const float*)d_in[14];

    char* ws = (char*)d_ws;
    float* WihT_f = (float*)ws;                 ws += (size_t)En * Gn * 4;      // 1,228,800
    float* WihT_b = (float*)ws;                 ws += (size_t)En * Gn * 4;
    unsigned int* q_f = (unsigned int*)ws;      ws += 262144;                   // 256 KB
    unsigned int* q_b = (unsigned int*)ws;      ws += 262144;
    float* scl_f = (float*)ws;                  ws += 4096;
    float* scl_b = (float*)ws;                  ws += 4096;
    unsigned short* Pf = (unsigned short*)ws;   ws += (size_t)Vn * Gn * 2;      // 20,480,000
    unsigned short* Pb = (unsigned short*)ws;   ws += (size_t)Vn * Gn * 2;
    float* em_pf = (float*)ws;                  ws += (size_t)Tn * Bn * Ln * 4; // 2,359,296
    float* em_pb = (float*)ws;                  ws += (size_t)Tn * Bn * Ln * 4;
    float* score = (float*)ws;                  ws += 512;
    float* logZ = (float*)ws;                   ws += 512;

    k_transpose_wih<<<dim3(1200, 2), 256, 0, stream>>>(Wih_f, Wih_b, WihT_f, WihT_b);
    k_quant_whh<<<dim3(1024, 2), 64, 0, stream>>>(Whh_f, Whh_b, q_f, q_b, scl_f, scl_b);
    k_proj<<<dim3(625, 4, 2), 256, 0, stream>>>(emb, WihT_f, WihT_b, b_f, b_b, Pf, Pb);
    k_lstm<<<256, 512, 0, stream>>>(ids, (const uint4*)q_f, (const uint4*)q_b,
                                    scl_f, scl_b, Pf, Pb, Wc, em_pf, em_pb);
    k_crf_den<<<128, 64, 0, stream>>>(em_pf, em_pb, bc, msk, trans, st, en, logZ);
    k_crf_num<<<128, 64, 0, stream>>>(em_pf, em_pb, bc, lbl, msk, trans, st, en, score);
    k_final<<<1, 128, 0, stream>>>(score, logZ, (float*)d_out);
}

// Round 6
// 1561.449 us; speedup vs baseline: 1.0567x; 1.0567x over previous
//
#include <hip/hip_runtime.h>
#include <hip/hip_bf16.h>

#define Vn 10000
#define En 300
#define Hn 256
#define Gn 1024   // 4*H
#define Ln 9
#define Bn 128
#define Tn 512

static __device__ __forceinline__ float bf2f(unsigned short u) {
    return __uint_as_float(((unsigned int)u) << 16);
}
static __device__ __forceinline__ unsigned short f2bf(float f) {
    unsigned int x = __float_as_uint(f);
    return (unsigned short)((x + 0x7FFFu + ((x >> 16) & 1u)) >> 16);
}
static __device__ __forceinline__ float sigm(float x) {
    return 1.f / (1.f + __expf(-x));
}
static __device__ __forceinline__ float tanh_fast(float x) {
    return 2.f / (1.f + __expf(-2.f * x)) - 1.f;
}
static __device__ __forceinline__ int dot4(unsigned int w, int h, int acc) {
    return __builtin_amdgcn_sdot4((int)w, h, acc, false);
}

// ---- transpose Wih (1024,300) -> WihT (300,1024), f32 ----
__global__ __launch_bounds__(256) void k_transpose_wih(
    const float* __restrict__ Wf, const float* __restrict__ Wb,
    float* __restrict__ Tf, float* __restrict__ Tb) {
    int n = blockIdx.x * 256 + threadIdx.x;          // < 307200
    const float* src = blockIdx.y ? Wb : Wf;
    float* dst = blockIdx.y ? Tb : Tf;
    int e = n / Gn, j = n % Gn;
    dst[n] = src[j * En + e];
}

// ---- quantize Whh (1024,256) f32 -> i8, per-gate-row scale ----
// Layout: dword d (k=4d..4d+3) of row j at uint index ((d>>2)*1024 + j)*4 + (d&3)
// i.e. uint4 tiles [d4][1024]; k_lstm thread j reads tiles at d4*1024 + j.
__global__ __launch_bounds__(64) void k_quant_whh(
    const float* __restrict__ Wf, const float* __restrict__ Wb,
    unsigned int* __restrict__ q_f, unsigned int* __restrict__ q_b,
    float* __restrict__ scl_f, float* __restrict__ scl_b) {
    int j = blockIdx.x;                 // 0..1023 (gate-row)
    int dir = blockIdx.y;
    int lane = threadIdx.x;             // 0..63 = dword index d
    const float* W = dir ? Wb : Wf;
    unsigned int* dst = dir ? q_b : q_f;
    float4 w = *(const float4*)&W[(size_t)j * Hn + 4 * lane];
    float m = fmaxf(fmaxf(fabsf(w.x), fabsf(w.y)), fmaxf(fabsf(w.z), fabsf(w.w)));
    #pragma unroll
    for (int sft = 32; sft >= 1; sft >>= 1) m = fmaxf(m, __shfl_xor(m, sft, 64));
    float inv = (m > 0.f) ? (127.f / m) : 0.f;
    int q0 = (int)rintf(w.x * inv), q1 = (int)rintf(w.y * inv);
    int q2 = (int)rintf(w.z * inv), q3 = (int)rintf(w.w * inv);
    unsigned int d = (q0 & 255) | ((q1 & 255) << 8) | ((q2 & 255) << 16) | ((q3 & 255) << 24);
    dst[(size_t)((lane >> 2) * 1024 + j) * 4 + (lane & 3)] = d;
    if (lane == 0) (dir ? scl_b : scl_f)[j] = m / 16129.f;
}

// ---- P = emb @ WihT + b : (10000, 1024) bf16 per direction ----
// 32 v-rows per block (8 per ty-group): WT slice re-read 313x not 625x.
__global__ __launch_bounds__(256) void k_proj(
    const float* __restrict__ emb,
    const float* __restrict__ WihT_f, const float* __restrict__ WihT_b,
    const float* __restrict__ b_f, const float* __restrict__ b_b,
    unsigned short* __restrict__ Pf, unsigned short* __restrict__ Pb) {
    int tid = threadIdx.x;
    int tx = tid & 63, ty = tid >> 6;
    int dir = blockIdx.z;
    const float* WT = dir ? WihT_b : WihT_f;
    const float* bias = dir ? b_b : b_f;
    unsigned short* P = dir ? Pb : Pf;
    int v0 = blockIdx.x * 32 + ty * 8;               // 313 blocks, tail-guarded
    int j0 = blockIdx.y * 256 + tx * 4;
    const float* erow[8];
    #pragma unroll
    for (int r = 0; r < 8; ++r) {
        int vr = v0 + r; if (vr > Vn - 1) vr = Vn - 1;
        erow[r] = emb + (size_t)vr * En;
    }
    float4 acc[8];
    #pragma unroll
    for (int r = 0; r < 8; ++r) acc[r] = make_float4(0.f, 0.f, 0.f, 0.f);
    for (int e0 = 0; e0 < En; e0 += 4) {             // 300 = 75*4 exact
        float4 w0 = *(const float4*)&WT[(size_t)(e0 + 0) * Gn + j0];
        float4 w1 = *(const float4*)&WT[(size_t)(e0 + 1) * Gn + j0];
        float4 w2 = *(const float4*)&WT[(size_t)(e0 + 2) * Gn + j0];
        float4 w3 = *(const float4*)&WT[(size_t)(e0 + 3) * Gn + j0];
        #pragma unroll
        for (int r = 0; r < 8; ++r) {
            float4 a = *(const float4*)&erow[r][e0];
            acc[r].x += a.x*w0.x + a.y*w1.x + a.z*w2.x + a.w*w3.x;
            acc[r].y += a.x*w0.y + a.y*w1.y + a.z*w2.y + a.w*w3.y;
            acc[r].z += a.x*w0.z + a.y*w1.z + a.z*w2.z + a.w*w3.z;
            acc[r].w += a.x*w0.w + a.y*w1.w + a.z*w2.w + a.w*w3.w;
        }
    }
    float4 bb = *(const float4*)&bias[j0];
    #pragma unroll
    for (int r = 0; r < 8; ++r) {
        if (v0 + r < Vn) {
            ushort4 o;
            o.x = f2bf(acc[r].x + bb.x); o.y = f2bf(acc[r].y + bb.y);
            o.z = f2bf(acc[r].z + bb.z); o.w = f2bf(acc[r].w + bb.w);
            *(ushort4*)&P[(size_t)(v0 + r) * Gn + j0] = o;
        }
    }
}

// ---- persistent BiLSTM recurrence: 256 WGs = 2 dir x 128 batch, 512 thr ----
// Thread j owns gate-rows {j, j+512}: 32 uint4 weights PINNED in VGPRs via an
// empty asm that makes the load results non-rederivable (defeats remat, the
// r4/r5 failure). h-broadcast: ONE ds_read_b128 per wave + v_readlane -> SGPR
// operand of v_dot4. Emissions fused (waves 4..7).
__global__ __launch_bounds__(512, 2) void k_lstm(
    const int* __restrict__ ids,
    const uint4* __restrict__ q_f, const uint4* __restrict__ q_b,
    const float* __restrict__ scl_f, const float* __restrict__ scl_b,
    const unsigned short* __restrict__ Pf, const unsigned short* __restrict__ Pb,
    const float* __restrict__ Wc,
    float* __restrict__ em_pf, float* __restrict__ em_pb) {
    __shared__ float g_stage[Gn];            // 4 KB gate preacts
    __shared__ float hstage[Hn];             // 1 KB f32 h for emission dot
    __shared__ uint4 h8v[16];                // 256 B i8 h (dword d = units 4d..4d+3)
    __shared__ int ids_lds[Tn];              // 2 KB
    __shared__ float wc_lds[Ln][Hn];         // 9 KB this dir's half of Wc
    int tid = threadIdx.x;
    int dir = blockIdx.x >> 7;
    int batch = blockIdx.x & 127;
    const uint4* q = dir ? q_b : q_f;
    const unsigned short* P = dir ? Pb : Pf;
    float* em_p = dir ? em_pb : em_pf;

    uint4 wA[16], wB[16];
    #pragma unroll
    for (int d4 = 0; d4 < 16; ++d4) {
        wA[d4] = q[(size_t)d4 * 1024 + tid];
        wB[d4] = q[(size_t)d4 * 1024 + tid + 512];
    }
    // PIN: make load results opaque so the compiler cannot re-load them
    // inside the step loop (r4/r5: remat kept VGPR at 48/88 and re-streamed
    // 256 KB/step from L2). After this, wA/wB MUST stay in VGPRs.
    #pragma unroll
    for (int d4 = 0; d4 < 16; ++d4) {
        asm volatile("" : "+v"(wA[d4].x), "+v"(wA[d4].y), "+v"(wA[d4].z), "+v"(wA[d4].w));
        asm volatile("" : "+v"(wB[d4].x), "+v"(wB[d4].y), "+v"(wB[d4].z), "+v"(wB[d4].w));
    }
    const float* scl = dir ? scl_b : scl_f;
    float sc0 = scl[tid], sc1 = scl[tid + 512];
    ids_lds[tid] = ids[batch * Tn + tid];                 // Tn == 512 exactly
    for (int i = tid; i < Ln * Hn; i += 512)
        wc_lds[i >> 8][i & 255] = Wc[(size_t)(i >> 8) * 512 + dir * 256 + (i & 255)];
    if (tid < 16) { uint4 z = {0u, 0u, 0u, 0u}; h8v[tid] = z; }
    float c = 0.f;
    __syncthreads();

    int t0 = dir ? (Tn - 1) : 0;
    float p0 = bf2f(P[(size_t)ids_lds[t0] * Gn + tid]);
    float p1 = bf2f(P[(size_t)ids_lds[t0] * Gn + tid + 512]);

    for (int s = 0; s < Tn; ++s) {
        int t = dir ? (Tn - 1 - s) : s;
        int s2 = (s + 1 < Tn) ? s + 1 : Tn - 1;
        int t2 = dir ? (Tn - 1 - s2) : s2;
        const unsigned short* pr = P + (size_t)ids_lds[t2] * Gn;
        unsigned short n0 = pr[tid], n1 = pr[tid + 512]; // next-step prefetch

        uint4 hv = h8v[tid & 15];                        // ONE ds_read_b128/wave
        int accA = 0, accB = 0;
        #pragma unroll
        for (int d4 = 0; d4 < 16; ++d4) {
            int hX = __builtin_amdgcn_readlane((int)hv.x, d4);
            int hY = __builtin_amdgcn_readlane((int)hv.y, d4);
            int hZ = __builtin_amdgcn_readlane((int)hv.z, d4);
            int hW = __builtin_amdgcn_readlane((int)hv.w, d4);
            accA = dot4(wA[d4].x, hX, accA);
            accA = dot4(wA[d4].y, hY, accA);
            accA = dot4(wA[d4].z, hZ, accA);
            accA = dot4(wA[d4].w, hW, accA);
            accB = dot4(wB[d4].x, hX, accB);
            accB = dot4(wB[d4].y, hY, accB);
            accB = dot4(wB[d4].z, hZ, accB);
            accB = dot4(wB[d4].w, hW, accB);
        }
        g_stage[tid]       = sc0 * (float)accA + p0;
        g_stage[tid + 512] = sc1 * (float)accB + p1;
        __syncthreads();                                 // B1: gates ready
        if (tid < Hn) {
            float gi = g_stage[tid];
            float gf = g_stage[tid + 256];
            float gg = g_stage[tid + 512];
            float go = g_stage[tid + 768];
            float cn = sigm(gf) * c + sigm(gi) * tanh_fast(gg);
            float hn = sigm(go) * tanh_fast(cn);
            c = cn;
            hstage[tid] = hn;
            ((char*)h8v)[tid] = (char)(int)rintf(127.f * hn);
        }
        __syncthreads();                                 // B2: new h visible
        if (tid >= 256) {                                // waves 4..7: emissions
            int wv = (tid >> 6) - 4;                     // 0..3
            int lane = tid & 63;
            int l1 = (wv == 3) ? 9 : 2 * wv + 2;
            for (int l = 2 * wv; l < l1; ++l) {
                float4 h4 = *(const float4*)&hstage[lane * 4];
                float4 w4 = *(const float4*)&wc_lds[l][lane * 4];
                float p = h4.x * w4.x + h4.y * w4.y + h4.z * w4.z + h4.w * w4.w;
                #pragma unroll
                for (int m = 32; m >= 1; m >>= 1) p += __shfl_xor(p, m, 64);
                if (lane == 0) em_p[((size_t)t * Bn + batch) * Ln + l] = p;
            }
        }
        p0 = bf2f(n0); p1 = bf2f(n1);
    }
}

// ---- CRF denominator: 128 single-wave WGs, shuffle-based, barrier-free ----
// alpha for label j lives in lane j (j<9). alpha_i broadcasts via __shfl.
__global__ __launch_bounds__(64) void k_crf_den(
    const float* __restrict__ pf, const float* __restrict__ pb,
    const float* __restrict__ bc, const int* __restrict__ mask,
    const float* __restrict__ trans, const float* __restrict__ start,
    const float* __restrict__ endt, float* __restrict__ logZ) {
    int b = blockIdx.x, j = threadIdx.x;
    int jj = (j < Ln) ? j : Ln - 1;                  // clamp for safe loads
    float trj[Ln];
    #pragma unroll
    for (int i = 0; i < Ln; ++i) trj[i] = trans[i * Ln + jj];
    float bcj = bc[jj];
    size_t ix0 = (size_t)b * Ln + jj;
    float alpha = start[jj] + pf[ix0] + pb[ix0] + bcj;
    // software pipeline depth 2 on emissions + mask
    size_t ix1 = (size_t)(1 * Bn + b) * Ln + jj;
    size_t ix2 = (size_t)(2 * Bn + b) * Ln + jj;
    float e1 = pf[ix1] + pb[ix1] + bcj;
    float e2 = pf[ix2] + pb[ix2] + bcj;
    int m1 = mask[b * Tn + 1];
    int m2 = mask[b * Tn + 2];
    for (int t = 1; t < Tn; ++t) {
        float s0 = __shfl(alpha, 0, 64) + trj[0];
        float s1 = __shfl(alpha, 1, 64) + trj[1];
        float s2 = __shfl(alpha, 2, 64) + trj[2];
        float s3 = __shfl(alpha, 3, 64) + trj[3];
        float s4 = __shfl(alpha, 4, 64) + trj[4];
        float s5 = __shfl(alpha, 5, 64) + trj[5];
        float s6 = __shfl(alpha, 6, 64) + trj[6];
        float s7 = __shfl(alpha, 7, 64) + trj[7];
        float s8 = __shfl(alpha, 8, 64) + trj[8];
        float mx = fmaxf(fmaxf(fmaxf(s0, s1), fmaxf(s2, s3)),
                         fmaxf(fmaxf(s4, s5), fmaxf(fmaxf(s6, s7), s8)));
        float sum = __expf(s0 - mx) + __expf(s1 - mx) + __expf(s2 - mx)
                  + __expf(s3 - mx) + __expf(s4 - mx) + __expf(s5 - mx)
                  + __expf(s6 - mx) + __expf(s7 - mx) + __expf(s8 - mx);
        float nxt = mx + __logf(sum) + e1;
        if (m1) alpha = nxt;
        e1 = e2; m1 = m2;
        int t2 = (t + 2 < Tn) ? t + 2 : Tn - 1;
        size_t ixn = (size_t)(t2 * Bn + b) * Ln + jj;
        e2 = pf[ixn] + pb[ixn] + bcj;
        m2 = mask[b * Tn + t2];
    }
    float s = (j < Ln) ? alpha + endt[j] : -1e30f;
    float mx = s;
    #pragma unroll
    for (int d = 32; d >= 1; d >>= 1) mx = fmaxf(mx, __shfl_xor(mx, d, 64));
    float sm = __expf(s - mx);
    #pragma unroll
    for (int d = 32; d >= 1; d >>= 1) sm += __shfl_xor(sm, d, 64);
    if (j == 0) logZ[b] = mx + __logf(sm);
}

// ---- CRF numerator: gold-path score is a plain sum -> fully parallel over t ----
__global__ __launch_bounds__(64) void k_crf_num(
    const float* __restrict__ pf, const float* __restrict__ pb,
    const float* __restrict__ bc, const int* __restrict__ labels,
    const int* __restrict__ mask, const float* __restrict__ trans,
    const float* __restrict__ start, const float* __restrict__ endt,
    float* __restrict__ score) {
    int b = blockIdx.x, lane = threadIdx.x;
    float acc = 0.f; int cnt = 0;
    for (int t = lane; t < Tn; t += 64) {
        int tag = labels[b * Tn + t];
        int mt = mask[b * Tn + t];
        cnt += mt;
        size_t ix = (size_t)(t * Bn + b) * Ln + tag;
        float e = pf[ix] + pb[ix] + bc[tag];
        if (t == 0) {
            acc += start[tag] + e;
        } else {
            int prev = labels[b * Tn + t - 1];
            if (mt) acc += trans[prev * Ln + tag] + e;
        }
    }
    #pragma unroll
    for (int m = 32; m >= 1; m >>= 1) {
        acc += __shfl_xor(acc, m, 64);
        cnt += __shfl_xor(cnt, m, 64);
    }
    if (lane == 0) {
        int send = cnt - 1;
        int last = labels[b * Tn + send];
        score[b] = acc + endt[last];
    }
}

__global__ __launch_bounds__(128) void k_final(
    const float* __restrict__ score, const float* __restrict__ logZ,
    float* __restrict__ out) {
    __shared__ float s_s[128];
    int tid = threadIdx.x;
    s_s[tid] = score[tid] - logZ[tid];
    #pragma unroll
    for (int m = 64; m >= 1; m >>= 1) {
        __syncthreads();
        if (tid < m) s_s[tid] += s_s[tid + m];
    }
    if (tid == 0) out[0] = -s_s[0] / (float)Bn;
}

extern "C" void kernel_launch(void* const* d_in, const int* in_sizes, int n_in,
                              void* d_out, int out_size, void* d_ws, size_t ws_size,
                              hipStream_t stream) {
    const int* ids = (const int*)d_in[0];
    const int* msk = (const int*)d_in[1];
    const int* lbl = (const int*)d_in[2];
    const float* emb = (const float*)d_in[3];
    const float* Wih_f = (const float*)d_in[4];
    const float* Whh_f = (const float*)d_in[5];
    const float* b_f = (const float*)d_in[6];
    const float* Wih_b = (const float*)d_in[7];
    const float* Whh_b = (const float*)d_in[8];
    const float* b_b = (const float*)d_in[9];
    const float* Wc = (const float*)d_in[10];
    const float* bc = (const float*)d_in[11];
    const float* trans = (const float*)d_in[12];
    const float* st = (const float*)d_in[13];
    const float* en = (const float*)d_in[14];

    char* ws = (char*)d_ws;
    float* WihT_f = (float*)ws;                 ws += (size_t)En * Gn * 4;      // 1,228,800
    float* WihT_b = (float*)ws;                 ws += (size_t)En * Gn * 4;
    unsigned int* q_f = (unsigned int*)ws;      ws += 262144;                   // 256 KB
    unsigned int* q_b = (unsigned int*)ws;      ws += 262144;
    float* scl_f = (float*)ws;                  ws += 4096;
    float* scl_b = (float*)ws;                  ws += 4096;
    unsigned short* Pf = (unsigned short*)ws;   ws += (size_t)Vn * Gn * 2;      // 20,480,000
    unsigned short* Pb = (unsigned short*)ws;   ws += (size_t)Vn * Gn * 2;
    float* em_pf = (float*)ws;                  ws += (size_t)Tn * Bn * Ln * 4; // 2,359,296
    float* em_pb = (float*)ws;                  ws += (size_t)Tn * Bn * Ln * 4;
    float* score = (float*)ws;                  ws += 512;
    float* logZ = (float*)ws;                   ws += 512;

    k_transpose_wih<<<dim3(1200, 2), 256, 0, stream>>>(Wih_f, Wih_b, WihT_f, WihT_b);
    k_quant_whh<<<dim3(1024, 2), 64, 0, stream>>>(Whh_f, Whh_b, q_f, q_b, scl_f, scl_b);
    k_proj<<<dim3(313, 4, 2), 256, 0, stream>>>(emb, WihT_f, WihT_b, b_f, b_b, Pf, Pb);
    k_lstm<<<256, 512, 0, stream>>>(ids, (const uint4*)q_f, (const uint4*)q_b,
                                    scl_f, scl_b, Pf, Pb, Wc, em_pf, em_pb);
    k_crf_den<<<128, 64, 0, stream>>>(em_pf, em_pb, bc, msk, trans, st, en, logZ);
    k_crf_num<<<128, 64, 0, stream>>>(em_pf, em_pb, bc, lbl, msk, trans, st, en, score);
    k_final<<<1, 128, 0, stream>>>(score, logZ, (float*)d_out);
}

// Round 7
// 1312.468 us; speedup vs baseline: 1.2572x; 1.1897x over previous
//
#include <hip/hip_runtime.h>
#include <hip/hip_bf16.h>

#define Vn 10000
#define En 300
#define Hn 256
#define Gn 1024   // 4*H
#define Ln 9
#define Bn 128
#define Tn 512

#if defined(__has_builtin)
#  if __has_builtin(__builtin_amdgcn_sdot8)
#    define HAS_SDOT8 1
#  endif
#endif
#ifndef HAS_SDOT8
#  define HAS_SDOT8 0
#endif

static __device__ __forceinline__ float bf2f(unsigned short u) {
    return __uint_as_float(((unsigned int)u) << 16);
}
static __device__ __forceinline__ unsigned short f2bf(float f) {
    unsigned int x = __float_as_uint(f);
    return (unsigned short)((x + 0x7FFFu + ((x >> 16) & 1u)) >> 16);
}
static __device__ __forceinline__ float sigm(float x) {
    return 1.f / (1.f + __expf(-x));
}
static __device__ __forceinline__ float tanh_fast(float x) {
    return 2.f / (1.f + __expf(-2.f * x)) - 1.f;
}
// i4x8 dot: both operands are 8 packed signed nibbles
static __device__ __forceinline__ int dot8(unsigned int w, int h, int acc) {
#if HAS_SDOT8
    return __builtin_amdgcn_sdot8((int)w, h, acc, false);
#else
    unsigned int wl = ((w & 0x0F0F0F0Fu) ^ 0x08080808u) - 0x08080808u;
    unsigned int wh = (((w >> 4) & 0x0F0F0F0Fu) ^ 0x08080808u) - 0x08080808u;
    unsigned int hl = (((unsigned)h & 0x0F0F0F0Fu) ^ 0x08080808u) - 0x08080808u;
    unsigned int hh = ((((unsigned)h >> 4) & 0x0F0F0F0Fu) ^ 0x08080808u) - 0x08080808u;
    acc = __builtin_amdgcn_sdot4((int)wl, (int)hl, acc, false);
    return __builtin_amdgcn_sdot4((int)wh, (int)hh, acc, false);
#endif
}

// ---- transpose Wih (1024,300) -> WihT (300,1024), f32 ----
__global__ __launch_bounds__(256) void k_transpose_wih(
    const float* __restrict__ Wf, const float* __restrict__ Wb,
    float* __restrict__ Tf, float* __restrict__ Tb) {
    int n = blockIdx.x * 256 + threadIdx.x;          // < 307200
    const float* src = blockIdx.y ? Wb : Wf;
    float* dst = blockIdx.y ? Tb : Tf;
    int e = n / Gn, j = n % Gn;
    dst[n] = src[j * En + e];
}

// ---- quantize Whh (1024,256) f32 -> i4 nibbles, per-gate-row scale ----
// dword e of row j (k = 8e..8e+7, nibble i = k=8e+i) at uint index
// ((e>>2)*1024 + j)*4 + (e&3)  i.e. uint4 tiles [e4][1024].
// gate = scl[j] * sdot8sum + P, scl[j] = rowmax/49 (w_q in [-7,7], h_q in [-7,7]).
__global__ __launch_bounds__(64) void k_quant_whh(
    const float* __restrict__ Wf, const float* __restrict__ Wb,
    unsigned int* __restrict__ q_f, unsigned int* __restrict__ q_b,
    float* __restrict__ scl_f, float* __restrict__ scl_b) {
    int j = blockIdx.x;                 // 0..1023 (gate-row)
    int dir = blockIdx.y;
    int lane = threadIdx.x;             // lanes 0..31 = dword index e
    const float* W = dir ? Wb : Wf;
    unsigned int* dst = dir ? q_b : q_f;
    float w8[8];
    float m = 0.f;
    if (lane < 32) {
        float4 wlo = *(const float4*)&W[(size_t)j * Hn + 8 * lane];
        float4 whi = *(const float4*)&W[(size_t)j * Hn + 8 * lane + 4];
        w8[0] = wlo.x; w8[1] = wlo.y; w8[2] = wlo.z; w8[3] = wlo.w;
        w8[4] = whi.x; w8[5] = whi.y; w8[6] = whi.z; w8[7] = whi.w;
        #pragma unroll
        for (int i = 0; i < 8; ++i) m = fmaxf(m, fabsf(w8[i]));
    }
    #pragma unroll
    for (int sft = 32; sft >= 1; sft >>= 1) m = fmaxf(m, __shfl_xor(m, sft, 64));
    float inv = (m > 0.f) ? (7.f / m) : 0.f;
    if (lane < 32) {
        unsigned int d = 0;
        #pragma unroll
        for (int i = 0; i < 8; ++i) {
            int qi = (int)rintf(w8[i] * inv);
            d |= ((unsigned int)(qi & 0xF)) << (4 * i);
        }
        dst[(size_t)((lane >> 2) * 1024 + j) * 4 + (lane & 3)] = d;
    }
    if (lane == 0) (dir ? scl_b : scl_f)[j] = m / 49.f;
}

// ---- P = emb @ WihT + b : (10000, 1024) bf16 per direction ----
__global__ __launch_bounds__(256) void k_proj(
    const float* __restrict__ emb,
    const float* __restrict__ WihT_f, const float* __restrict__ WihT_b,
    const float* __restrict__ b_f, const float* __restrict__ b_b,
    unsigned short* __restrict__ Pf, unsigned short* __restrict__ Pb) {
    int tid = threadIdx.x;
    int tx = tid & 63, ty = tid >> 6;
    int dir = blockIdx.z;
    const float* WT = dir ? WihT_b : WihT_f;
    const float* bias = dir ? b_b : b_f;
    unsigned short* P = dir ? Pb : Pf;
    int v0 = blockIdx.x * 32 + ty * 8;               // 313 blocks, tail-guarded
    int j0 = blockIdx.y * 256 + tx * 4;
    const float* erow[8];
    #pragma unroll
    for (int r = 0; r < 8; ++r) {
        int vr = v0 + r; if (vr > Vn - 1) vr = Vn - 1;
        erow[r] = emb + (size_t)vr * En;
    }
    float4 acc[8];
    #pragma unroll
    for (int r = 0; r < 8; ++r) acc[r] = make_float4(0.f, 0.f, 0.f, 0.f);
    for (int e0 = 0; e0 < En; e0 += 4) {             // 300 = 75*4 exact
        float4 w0 = *(const float4*)&WT[(size_t)(e0 + 0) * Gn + j0];
        float4 w1 = *(const float4*)&WT[(size_t)(e0 + 1) * Gn + j0];
        float4 w2 = *(const float4*)&WT[(size_t)(e0 + 2) * Gn + j0];
        float4 w3 = *(const float4*)&WT[(size_t)(e0 + 3) * Gn + j0];
        #pragma unroll
        for (int r = 0; r < 8; ++r) {
            float4 a = *(const float4*)&erow[r][e0];
            acc[r].x += a.x*w0.x + a.y*w1.x + a.z*w2.x + a.w*w3.x;
            acc[r].y += a.x*w0.y + a.y*w1.y + a.z*w2.y + a.w*w3.y;
            acc[r].z += a.x*w0.z + a.y*w1.z + a.z*w2.z + a.w*w3.z;
            acc[r].w += a.x*w0.w + a.y*w1.w + a.z*w2.w + a.w*w3.w;
        }
    }
    float4 bb = *(const float4*)&bias[j0];
    #pragma unroll
    for (int r = 0; r < 8; ++r) {
        if (v0 + r < Vn) {
            ushort4 o;
            o.x = f2bf(acc[r].x + bb.x); o.y = f2bf(acc[r].y + bb.y);
            o.z = f2bf(acc[r].z + bb.z); o.w = f2bf(acc[r].w + bb.w);
            *(ushort4*)&P[(size_t)(v0 + r) * Gn + j0] = o;
        }
    }
}

// ---- persistent BiLSTM recurrence: 256 WGs = 2 dir x 128 batch, 512 thr ----
// i4 weights: thread j owns gate-rows {j, j+512} = 64 dwords (fits the ~90-VGPR
// budget the allocator actually grants -> resident, no per-step L2 stream).
// h as i4 nibbles in 128 B of LDS: 1 ds_read_b128/wave + readlane -> sdot8.
// Emissions fused (waves 4..7).
__global__ __launch_bounds__(512, 2) void k_lstm(
    const int* __restrict__ ids,
    const uint4* __restrict__ q_f, const uint4* __restrict__ q_b,
    const float* __restrict__ scl_f, const float* __restrict__ scl_b,
    const unsigned short* __restrict__ Pf, const unsigned short* __restrict__ Pb,
    const float* __restrict__ Wc,
    float* __restrict__ em_pf, float* __restrict__ em_pb) {
    __shared__ float g_stage[Gn];            // 4 KB gate preacts
    __shared__ float hstage[Hn];             // 1 KB f32 h for emission dot
    __shared__ uint4 h4v[8];                 // 128 B i4 h (dword e = units 8e..8e+7)
    __shared__ int ids_lds[Tn];              // 2 KB
    __shared__ float wc_lds[Ln][Hn];         // 9 KB this dir's half of Wc
    int tid = threadIdx.x;
    int dir = blockIdx.x >> 7;
    int batch = blockIdx.x & 127;
    const uint4* q = dir ? q_b : q_f;
    const unsigned short* P = dir ? Pb : Pf;
    float* em_p = dir ? em_pb : em_pf;

    unsigned int wA[32], wB[32];
    #pragma unroll
    for (int d = 0; d < 8; ++d) {
        uint4 va = q[(size_t)d * 1024 + tid];
        uint4 vb = q[(size_t)d * 1024 + tid + 512];
        wA[4*d+0] = va.x; wA[4*d+1] = va.y; wA[4*d+2] = va.z; wA[4*d+3] = va.w;
        wB[4*d+0] = vb.x; wB[4*d+1] = vb.y; wB[4*d+2] = vb.z; wB[4*d+3] = vb.w;
    }
    #pragma unroll
    for (int d = 0; d < 32; ++d) {
        asm volatile("" : "+v"(wA[d]));
        asm volatile("" : "+v"(wB[d]));
    }
    const float* scl = dir ? scl_b : scl_f;
    float sc0 = scl[tid], sc1 = scl[tid + 512];
    ids_lds[tid] = ids[batch * Tn + tid];                 // Tn == 512 exactly
    for (int i = tid; i < Ln * Hn; i += 512)
        wc_lds[i >> 8][i & 255] = Wc[(size_t)(i >> 8) * 512 + dir * 256 + (i & 255)];
    if (tid < 8) { uint4 z = {0u, 0u, 0u, 0u}; h4v[tid] = z; }
    float c = 0.f;
    __syncthreads();

    int t0 = dir ? (Tn - 1) : 0;
    float p0 = bf2f(P[(size_t)ids_lds[t0] * Gn + tid]);
    float p1 = bf2f(P[(size_t)ids_lds[t0] * Gn + tid + 512]);

    for (int s = 0; s < Tn; ++s) {
        int t = dir ? (Tn - 1 - s) : s;
        int s2 = (s + 1 < Tn) ? s + 1 : Tn - 1;
        int t2 = dir ? (Tn - 1 - s2) : s2;
        const unsigned short* pr = P + (size_t)ids_lds[t2] * Gn;
        unsigned short n0 = pr[tid], n1 = pr[tid + 512]; // next-step prefetch

        uint4 hq = h4v[tid & 7];                         // ONE ds_read_b128/wave
        int a0 = 0, a1 = 0, b0 = 0, b1 = 0;              // 4 chains, 16 deep
        #pragma unroll
        for (int g = 0; g < 8; ++g) {
            int h0 = __builtin_amdgcn_readlane((int)hq.x, g);
            int h1 = __builtin_amdgcn_readlane((int)hq.y, g);
            int h2 = __builtin_amdgcn_readlane((int)hq.z, g);
            int h3 = __builtin_amdgcn_readlane((int)hq.w, g);
            a0 = dot8(wA[4*g+0], h0, a0);
            a1 = dot8(wA[4*g+1], h1, a1);
            a0 = dot8(wA[4*g+2], h2, a0);
            a1 = dot8(wA[4*g+3], h3, a1);
            b0 = dot8(wB[4*g+0], h0, b0);
            b1 = dot8(wB[4*g+1], h1, b1);
            b0 = dot8(wB[4*g+2], h2, b0);
            b1 = dot8(wB[4*g+3], h3, b1);
        }
        g_stage[tid]       = sc0 * (float)(a0 + a1) + p0;
        g_stage[tid + 512] = sc1 * (float)(b0 + b1) + p1;
        __syncthreads();                                 // B1: gates ready
        if (tid < Hn) {
            float gi = g_stage[tid];
            float gf = g_stage[tid + 256];
            float gg = g_stage[tid + 512];
            float go = g_stage[tid + 768];
            float cn = sigm(gf) * c + sigm(gi) * tanh_fast(gg);
            float hn = sigm(go) * tanh_fast(cn);
            c = cn;
            hstage[tid] = hn;
            int qh = (int)rintf(7.f * hn);               // in [-7,7]
            int qo = __shfl_xor(qh, 1, 64);              // partner unit
            if ((tid & 1) == 0)
                ((char*)h4v)[tid >> 1] = (char)((qh & 0xF) | ((qo & 0xF) << 4));
        }
        __syncthreads();                                 // B2: new h visible
        if (tid >= 256) {                                // waves 4..7: emissions
            int wv = (tid >> 6) - 4;                     // 0..3
            int lane = tid & 63;
            int l1 = (wv == 3) ? 9 : 2 * wv + 2;
            for (int l = 2 * wv; l < l1; ++l) {
                float4 h4 = *(const float4*)&hstage[lane * 4];
                float4 w4 = *(const float4*)&wc_lds[l][lane * 4];
                float p = h4.x * w4.x + h4.y * w4.y + h4.z * w4.z + h4.w * w4.w;
                #pragma unroll
                for (int m = 32; m >= 1; m >>= 1) p += __shfl_xor(p, m, 64);
                if (lane == 0) em_p[((size_t)t * Bn + batch) * Ln + l] = p;
            }
        }
        p0 = bf2f(n0); p1 = bf2f(n1);
    }
}

// ---- CRF denominator: 64 single-wave WGs, 2 batches/wave (lanes 0-8, 32-40) ----
__global__ __launch_bounds__(64) void k_crf_den(
    const float* __restrict__ pf, const float* __restrict__ pb,
    const float* __restrict__ bc, const int* __restrict__ mask,
    const float* __restrict__ trans, const float* __restrict__ start,
    const float* __restrict__ endt, float* __restrict__ logZ) {
    int lane = threadIdx.x;
    int grp = lane >> 5;                             // 0 or 1
    int b = blockIdx.x + 64 * grp;
    int lj = lane & 31;
    int jj = (lj < Ln) ? lj : Ln - 1;                // clamp for safe loads
    int base = lane & 32;                            // shfl source base
    float trj[Ln];
    #pragma unroll
    for (int i = 0; i < Ln; ++i) trj[i] = trans[i * Ln + jj];
    float bcj = bc[jj];
    size_t ix0 = (size_t)b * Ln + jj;
    float alpha = start[jj] + pf[ix0] + pb[ix0] + bcj;
    size_t ix1 = (size_t)(1 * Bn + b) * Ln + jj;
    size_t ix2 = (size_t)(2 * Bn + b) * Ln + jj;
    float e1 = pf[ix1] + pb[ix1] + bcj;
    float e2 = pf[ix2] + pb[ix2] + bcj;
    int m1 = mask[b * Tn + 1];
    int m2 = mask[b * Tn + 2];
    for (int t = 1; t < Tn; ++t) {
        float s0 = __shfl(alpha, base + 0, 64) + trj[0];
        float s1 = __shfl(alpha, base + 1, 64) + trj[1];
        float s2 = __shfl(alpha, base + 2, 64) + trj[2];
        float s3 = __shfl(alpha, base + 3, 64) + trj[3];
        float s4 = __shfl(alpha, base + 4, 64) + trj[4];
        float s5 = __shfl(alpha, base + 5, 64) + trj[5];
        float s6 = __shfl(alpha, base + 6, 64) + trj[6];
        float s7 = __shfl(alpha, base + 7, 64) + trj[7];
        float s8 = __shfl(alpha, base + 8, 64) + trj[8];
        float mx = fmaxf(fmaxf(fmaxf(s0, s1), fmaxf(s2, s3)),
                         fmaxf(fmaxf(s4, s5), fmaxf(fmaxf(s6, s7), s8)));
        float sum = __expf(s0 - mx) + __expf(s1 - mx) + __expf(s2 - mx)
                  + __expf(s3 - mx) + __expf(s4 - mx) + __expf(s5 - mx)
                  + __expf(s6 - mx) + __expf(s7 - mx) + __expf(s8 - mx);
        float nxt = mx + __logf(sum) + e1;
        if (m1) alpha = nxt;
        e1 = e2; m1 = m2;
        int t2 = (t + 2 < Tn) ? t + 2 : Tn - 1;
        size_t ixn = (size_t)(t2 * Bn + b) * Ln + jj;
        e2 = pf[ixn] + pb[ixn] + bcj;
        m2 = mask[b * Tn + t2];
    }
    float s = (lj < Ln) ? alpha + endt[lj] : -1e30f;
    float mx = s;
    #pragma unroll
    for (int d = 16; d >= 1; d >>= 1) mx = fmaxf(mx, __shfl_xor(mx, d, 64));
    float sm = __expf(s - mx);
    #pragma unroll
    for (int d = 16; d >= 1; d >>= 1) sm += __shfl_xor(sm, d, 64);
    if (lj == 0) logZ[b] = mx + __logf(sm);
}

// ---- CRF numerator: gold-path score is a plain sum -> fully parallel over t ----
__global__ __launch_bounds__(64) void k_crf_num(
    const float* __restrict__ pf, const float* __restrict__ pb,
    const float* __restrict__ bc, const int* __restrict__ labels,
    const int* __restrict__ mask, const float* __restrict__ trans,
    const float* __restrict__ start, const float* __restrict__ endt,
    float* __restrict__ score) {
    int b = blockIdx.x, lane = threadIdx.x;
    float acc = 0.f; int cnt = 0;
    for (int t = lane; t < Tn; t += 64) {
        int tag = labels[b * Tn + t];
        int mt = mask[b * Tn + t];
        cnt += mt;
        size_t ix = (size_t)(t * Bn + b) * Ln + tag;
        float e = pf[ix] + pb[ix] + bc[tag];
        if (t == 0) {
            acc += start[tag] + e;
        } else {
            int prev = labels[b * Tn + t - 1];
            if (mt) acc += trans[prev * Ln + tag] + e;
        }
    }
    #pragma unroll
    for (int m = 32; m >= 1; m >>= 1) {
        acc += __shfl_xor(acc, m, 64);
        cnt += __shfl_xor(cnt, m, 64);
    }
    if (lane == 0) {
        int send = cnt - 1;
        int last = labels[b * Tn + send];
        score[b] = acc + endt[last];
    }
}

__global__ __launch_bounds__(128) void k_final(
    const float* __restrict__ score, const float* __restrict__ logZ,
    float* __restrict__ out) {
    __shared__ float s_s[128];
    int tid = threadIdx.x;
    s_s[tid] = score[tid] - logZ[tid];
    #pragma unroll
    for (int m = 64; m >= 1; m >>= 1) {
        __syncthreads();
        if (tid < m) s_s[tid] += s_s[tid + m];
    }
    if (tid == 0) out[0] = -s_s[0] / (float)Bn;
}

extern "C" void kernel_launch(void* const* d_in, const int* in_sizes, int n_in,
                              void* d_out, int out_size, void* d_ws, size_t ws_size,
                              hipStream_t stream) {
    const int* ids = (const int*)d_in[0];
    const int* msk = (const int*)d_in[1];
    const int* lbl = (const int*)d_in[2];
    const float* emb = (const float*)d_in[3];
    const float* Wih_f = (const float*)d_in[4];
    const float* Whh_f = (const float*)d_in[5];
    const float* b_f = (const float*)d_in[6];
    const float* Wih_b = (const float*)d_in[7];
    const float* Whh_b = (const float*)d_in[8];
    const float* b_b = (const float*)d_in[9];
    const float* Wc = (const float*)d_in[10];
    const float* bc = (const float*)d_in[11];
    const float* trans = (const float*)d_in[12];
    const float* st = (const float*)d_in[13];
    const float* en = (const float*)d_in[14];

    char* ws = (char*)d_ws;
    float* WihT_f = (float*)ws;                 ws += (size_t)En * Gn * 4;      // 1,228,800
    float* WihT_b = (float*)ws;                 ws += (size_t)En * Gn * 4;
    unsigned int* q_f = (unsigned int*)ws;      ws += 131072;                   // 128 KB (i4)
    unsigned int* q_b = (unsigned int*)ws;      ws += 131072;
    float* scl_f = (float*)ws;                  ws += 4096;
    float* scl_b = (float*)ws;                  ws += 4096;
    unsigned short* Pf = (unsigned short*)ws;   ws += (size_t)Vn * Gn * 2;      // 20,480,000
    unsigned short* Pb = (unsigned short*)ws;   ws += (size_t)Vn * Gn * 2;
    float* em_pf = (float*)ws;                  ws += (size_t)Tn * Bn * Ln * 4; // 2,359,296
    float* em_pb = (float*)ws;                  ws += (size_t)Tn * Bn * Ln * 4;
    float* score = (float*)ws;                  ws += 512;
    float* logZ = (float*)ws;                   ws += 512;

    k_transpose_wih<<<dim3(1200, 2), 256, 0, stream>>>(Wih_f, Wih_b, WihT_f, WihT_b);
    k_quant_whh<<<dim3(1024, 2), 64, 0, stream>>>(Whh_f, Whh_b, q_f, q_b, scl_f, scl_b);
    k_proj<<<dim3(313, 4, 2), 256, 0, stream>>>(emb, WihT_f, WihT_b, b_f, b_b, Pf, Pb);
    k_lstm<<<256, 512, 0, stream>>>(ids, (const uint4*)q_f, (const uint4*)q_b,
                                    scl_f, scl_b, Pf, Pb, Wc, em_pf, em_pb);
    k_crf_den<<<64, 64, 0, stream>>>(em_pf, em_pb, bc, msk, trans, st, en, logZ);
    k_crf_num<<<128, 64, 0, stream>>>(em_pf, em_pb, bc, lbl, msk, trans, st, en, score);
    k_final<<<1, 128, 0, stream>>>(score, logZ, (float*)d_out);
}

// Round 8
// 1093.997 us; speedup vs baseline: 1.5083x; 1.1997x over previous
//
#include <hip/hip_runtime.h>
#include <hip/hip_bf16.h>

#define Vn 10000
#define En 300
#define Hn 256
#define Gn 1024   // 4*H
#define Ln 9
#define Bn 128
#define Tn 512

#if defined(__has_builtin)
#  if __has_builtin(__builtin_amdgcn_sdot8)
#    define HAS_SDOT8 1
#  endif
#endif
#ifndef HAS_SDOT8
#  define HAS_SDOT8 0
#endif

static __device__ __forceinline__ float bf2f(unsigned short u) {
    return __uint_as_float(((unsigned int)u) << 16);
}
static __device__ __forceinline__ unsigned short f2bf(float f) {
    unsigned int x = __float_as_uint(f);
    return (unsigned short)((x + 0x7FFFu + ((x >> 16) & 1u)) >> 16);
}
static __device__ __forceinline__ float sigm(float x) {
    return 1.f / (1.f + __expf(-x));
}
static __device__ __forceinline__ float tanh_fast(float x) {
    return 2.f / (1.f + __expf(-2.f * x)) - 1.f;
}
// i4x8 dot: both operands are 8 packed signed nibbles
static __device__ __forceinline__ int dot8(unsigned int w, int h, int acc) {
#if HAS_SDOT8
    return __builtin_amdgcn_sdot8((int)w, h, acc, false);
#else
    unsigned int wl = ((w & 0x0F0F0F0Fu) ^ 0x08080808u) - 0x08080808u;
    unsigned int wh = (((w >> 4) & 0x0F0F0F0Fu) ^ 0x08080808u) - 0x08080808u;
    unsigned int hl = (((unsigned)h & 0x0F0F0F0Fu) ^ 0x08080808u) - 0x08080808u;
    unsigned int hh = ((((unsigned)h >> 4) & 0x0F0F0F0Fu) ^ 0x08080808u) - 0x08080808u;
    acc = __builtin_amdgcn_sdot4((int)wl, (int)hl, acc, false);
    return __builtin_amdgcn_sdot4((int)wh, (int)hh, acc, false);
#endif
}

// ---- transpose Wih (1024,300) -> WihT (300,1024), f32 ----
__global__ __launch_bounds__(256) void k_transpose_wih(
    const float* __restrict__ Wf, const float* __restrict__ Wb,
    float* __restrict__ Tf, float* __restrict__ Tb) {
    int n = blockIdx.x * 256 + threadIdx.x;          // < 307200
    const float* src = blockIdx.y ? Wb : Wf;
    float* dst = blockIdx.y ? Tb : Tf;
    int e = n / Gn, j = n % Gn;
    dst[n] = src[j * En + e];
}

// ---- quantize Whh (1024,256) f32 -> i4 nibbles, per-gate-row scale ----
// Split outputs: dwords e=0..15 (k=0..127) -> qr (register half, uint4 tiles
// [e>>2][1024]); dwords e=16..31 (k=128..255) -> ql (LDS half, same tiling).
// gate = scl[j] * sdot8sum + P, scl[j] = rowmax/49.
__global__ __launch_bounds__(64) void k_quant_whh(
    const float* __restrict__ Wf, const float* __restrict__ Wb,
    unsigned int* __restrict__ qr_f, unsigned int* __restrict__ ql_f,
    unsigned int* __restrict__ qr_b, unsigned int* __restrict__ ql_b,
    float* __restrict__ scl_f, float* __restrict__ scl_b) {
    int j = blockIdx.x;                 // 0..1023 (gate-row)
    int dir = blockIdx.y;
    int lane = threadIdx.x;             // lanes 0..31 = dword index e
    const float* W = dir ? Wb : Wf;
    float w8[8];
    float m = 0.f;
    if (lane < 32) {
        float4 wlo = *(const float4*)&W[(size_t)j * Hn + 8 * lane];
        float4 whi = *(const float4*)&W[(size_t)j * Hn + 8 * lane + 4];
        w8[0] = wlo.x; w8[1] = wlo.y; w8[2] = wlo.z; w8[3] = wlo.w;
        w8[4] = whi.x; w8[5] = whi.y; w8[6] = whi.z; w8[7] = whi.w;
        #pragma unroll
        for (int i = 0; i < 8; ++i) m = fmaxf(m, fabsf(w8[i]));
    }
    #pragma unroll
    for (int sft = 32; sft >= 1; sft >>= 1) m = fmaxf(m, __shfl_xor(m, sft, 64));
    float inv = (m > 0.f) ? (7.f / m) : 0.f;
    if (lane < 32) {
        unsigned int d = 0;
        #pragma unroll
        for (int i = 0; i < 8; ++i) {
            int qi = (int)rintf(w8[i] * inv);
            d |= ((unsigned int)(qi & 0xF)) << (4 * i);
        }
        if (lane < 16)
            (dir ? qr_b : qr_f)[(size_t)((lane >> 2) * 1024 + j) * 4 + (lane & 3)] = d;
        else {
            int e = lane - 16;
            (dir ? ql_b : ql_f)[(size_t)((e >> 2) * 1024 + j) * 4 + (e & 3)] = d;
        }
    }
    if (lane == 0) (dir ? scl_b : scl_f)[j] = m / 49.f;
}

// ---- P = emb @ WihT + b : (10000, 1024) bf16 per direction ----
__global__ __launch_bounds__(256) void k_proj(
    const float* __restrict__ emb,
    const float* __restrict__ WihT_f, const float* __restrict__ WihT_b,
    const float* __restrict__ b_f, const float* __restrict__ b_b,
    unsigned short* __restrict__ Pf, unsigned short* __restrict__ Pb) {
    int tid = threadIdx.x;
    int tx = tid & 63, ty = tid >> 6;
    int dir = blockIdx.z;
    const float* WT = dir ? WihT_b : WihT_f;
    const float* bias = dir ? b_b : b_f;
    unsigned short* P = dir ? Pb : Pf;
    int v0 = blockIdx.x * 32 + ty * 8;               // 313 blocks, tail-guarded
    int j0 = blockIdx.y * 256 + tx * 4;
    const float* erow[8];
    #pragma unroll
    for (int r = 0; r < 8; ++r) {
        int vr = v0 + r; if (vr > Vn - 1) vr = Vn - 1;
        erow[r] = emb + (size_t)vr * En;
    }
    float4 acc[8];
    #pragma unroll
    for (int r = 0; r < 8; ++r) acc[r] = make_float4(0.f, 0.f, 0.f, 0.f);
    for (int e0 = 0; e0 < En; e0 += 4) {             // 300 = 75*4 exact
        float4 w0 = *(const float4*)&WT[(size_t)(e0 + 0) * Gn + j0];
        float4 w1 = *(const float4*)&WT[(size_t)(e0 + 1) * Gn + j0];
        float4 w2 = *(const float4*)&WT[(size_t)(e0 + 2) * Gn + j0];
        float4 w3 = *(const float4*)&WT[(size_t)(e0 + 3) * Gn + j0];
        #pragma unroll
        for (int r = 0; r < 8; ++r) {
            float4 a = *(const float4*)&erow[r][e0];
            acc[r].x += a.x*w0.x + a.y*w1.x + a.z*w2.x + a.w*w3.x;
            acc[r].y += a.x*w0.y + a.y*w1.y + a.z*w2.y + a.w*w3.y;
            acc[r].z += a.x*w0.z + a.y*w1.z + a.z*w2.z + a.w*w3.z;
            acc[r].w += a.x*w0.w + a.y*w1.w + a.z*w2.w + a.w*w3.w;
        }
    }
    float4 bb = *(const float4*)&bias[j0];
    #pragma unroll
    for (int r = 0; r < 8; ++r) {
        if (v0 + r < Vn) {
            ushort4 o;
            o.x = f2bf(acc[r].x + bb.x); o.y = f2bf(acc[r].y + bb.y);
            o.z = f2bf(acc[r].z + bb.z); o.w = f2bf(acc[r].w + bb.w);
            *(ushort4*)&P[(size_t)(v0 + r) * Gn + j0] = o;
        }
    }
}

// ---- persistent BiLSTM recurrence: 256 WGs = 2 dir x 128 batch, 1024 thr ----
// Thread tid owns gate-row tid (32 i4 dwords = 128 B): 16 dwords pinned in
// VGPRs with IN-LOOP asm (loop-carried -> allocator must keep them live, not
// spill: the r5/r6/r7 failure was loop-invariant values spilled to scratch);
// 16 dwords streamed from LDS (64 KB, 4 x ds_read_b128/thread/step).
// h as i4 nibbles: 1 ds_read_b128/thread + readlane -> sdot8.
__global__ __launch_bounds__(1024, 4) void k_lstm(
    const int* __restrict__ ids,
    const uint4* __restrict__ qr_f, const uint4* __restrict__ ql_f,
    const uint4* __restrict__ qr_b, const uint4* __restrict__ ql_b,
    const float* __restrict__ scl_f, const float* __restrict__ scl_b,
    const unsigned short* __restrict__ Pf, const unsigned short* __restrict__ Pb,
    const float* __restrict__ Wc,
    float* __restrict__ em_pf, float* __restrict__ em_pb) {
    __shared__ uint4 wlds[4 * 1024];         // 64 KB streamed weight half (k=128..255)
    __shared__ float g_stage[Gn];            // 4 KB gate preacts
    __shared__ float hstage[Hn];             // 1 KB f32 h for emission dot
    __shared__ uint4 h4v[8];                 // 128 B i4 h (dword D = units 8D..8D+7)
    __shared__ int ids_lds[Tn];              // 2 KB
    __shared__ float wc_lds[Ln][Hn];         // 9 KB this dir's half of Wc
    int tid = threadIdx.x;
    int dir = blockIdx.x >> 7;
    int batch = blockIdx.x & 127;
    const uint4* qr = dir ? qr_b : qr_f;
    const uint4* ql = dir ? ql_b : ql_f;
    const unsigned short* P = dir ? Pb : Pf;
    float* em_p = dir ? em_pb : em_pf;

    unsigned int wReg[16];
    #pragma unroll
    for (int d4 = 0; d4 < 4; ++d4) {
        uint4 v = qr[(size_t)d4 * 1024 + tid];
        wReg[4*d4+0] = v.x; wReg[4*d4+1] = v.y; wReg[4*d4+2] = v.z; wReg[4*d4+3] = v.w;
        wlds[d4 * 1024 + tid] = ql[(size_t)d4 * 1024 + tid];
    }
    float sc = (dir ? scl_b : scl_f)[tid];
    if (tid < Tn) ids_lds[tid] = ids[batch * Tn + tid];
    for (int i = tid; i < Ln * Hn; i += 1024)
        wc_lds[i >> 8][i & 255] = Wc[(size_t)(i >> 8) * 512 + dir * 256 + (i & 255)];
    if (tid < 8) { uint4 z = {0u, 0u, 0u, 0u}; h4v[tid] = z; }
    float c = 0.f;
    __syncthreads();

    int t0 = dir ? (Tn - 1) : 0;
    float p = bf2f(P[(size_t)ids_lds[t0] * Gn + tid]);

    for (int s = 0; s < Tn; ++s) {
        // loop-carried pin: value flows through the asm each iteration, so the
        // allocator cannot treat wReg as re-loadable/spill-cheap loop-invariants
        #pragma unroll
        for (int d = 0; d < 16; ++d) asm volatile("" : "+v"(wReg[d]));

        int t = dir ? (Tn - 1 - s) : s;
        int s2 = (s + 1 < Tn) ? s + 1 : Tn - 1;
        int t2 = dir ? (Tn - 1 - s2) : s2;
        unsigned short nx = P[(size_t)ids_lds[t2] * Gn + tid];   // next-step prefetch

        uint4 hq  = h4v[tid & 7];                     // 1 ds_read_b128
        uint4 wv0 = wlds[tid];                        // 4 ds_read_b128 (k=128..255)
        uint4 wv1 = wlds[1024 + tid];
        uint4 wv2 = wlds[2048 + tid];
        uint4 wv3 = wlds[3072 + tid];

        int acc0 = 0, acc1 = 0;
        #pragma unroll
        for (int g = 0; g < 4; ++g) {                 // register half: h dwords 0..15
            int h0 = __builtin_amdgcn_readlane((int)hq.x, g);
            int h1 = __builtin_amdgcn_readlane((int)hq.y, g);
            int h2 = __builtin_amdgcn_readlane((int)hq.z, g);
            int h3 = __builtin_amdgcn_readlane((int)hq.w, g);
            acc0 = dot8(wReg[4*g+0], h0, acc0);
            acc1 = dot8(wReg[4*g+1], h1, acc1);
            acc0 = dot8(wReg[4*g+2], h2, acc0);
            acc1 = dot8(wReg[4*g+3], h3, acc1);
        }
        {                                             // LDS half: h dwords 16..31
            uint4 wv[4] = {wv0, wv1, wv2, wv3};
            #pragma unroll
            for (int g = 4; g < 8; ++g) {
                int h0 = __builtin_amdgcn_readlane((int)hq.x, g);
                int h1 = __builtin_amdgcn_readlane((int)hq.y, g);
                int h2 = __builtin_amdgcn_readlane((int)hq.z, g);
                int h3 = __builtin_amdgcn_readlane((int)hq.w, g);
                acc0 = dot8(wv[g-4].x, h0, acc0);
                acc1 = dot8(wv[g-4].y, h1, acc1);
                acc0 = dot8(wv[g-4].z, h2, acc0);
                acc1 = dot8(wv[g-4].w, h3, acc1);
            }
        }
        g_stage[tid] = sc * (float)(acc0 + acc1) + p;
        __syncthreads();                              // B1: gates ready
        if (tid < Hn) {
            float gi = g_stage[tid];
            float gf = g_stage[tid + 256];
            float gg = g_stage[tid + 512];
            float go = g_stage[tid + 768];
            float cn = sigm(gf) * c + sigm(gi) * tanh_fast(gg);
            float hn = sigm(go) * tanh_fast(cn);
            c = cn;
            hstage[tid] = hn;
            int qh = (int)rintf(7.f * hn);            // in [-7,7]
            int qo = __shfl_xor(qh, 1, 64);           // partner unit, same wave
            if ((tid & 1) == 0)
                ((char*)h4v)[tid >> 1] = (char)((qh & 0xF) | ((qo & 0xF) << 4));
        }
        __syncthreads();                              // B2: new h visible
        if (tid >= 448) {                             // waves 7..15: one label each
            int l = (tid >> 6) - 7;                   // 0..8
            int lane = tid & 63;
            float4 h4 = *(const float4*)&hstage[lane * 4];
            float4 w4 = *(const float4*)&wc_lds[l][lane * 4];
            float pe = h4.x * w4.x + h4.y * w4.y + h4.z * w4.z + h4.w * w4.w;
            #pragma unroll
            for (int m = 32; m >= 1; m >>= 1) pe += __shfl_xor(pe, m, 64);
            if (lane == 0) em_p[((size_t)t * Bn + batch) * Ln + l] = pe;
        }
        p = bf2f(nx);
    }
}

// ---- CRF denominator: 64 single-wave WGs, 2 batches/wave (lanes 0-8, 32-40) ----
__global__ __launch_bounds__(64) void k_crf_den(
    const float* __restrict__ pf, const float* __restrict__ pb,
    const float* __restrict__ bc, const int* __restrict__ mask,
    const float* __restrict__ trans, const float* __restrict__ start,
    const float* __restrict__ endt, float* __restrict__ logZ) {
    int lane = threadIdx.x;
    int grp = lane >> 5;                             // 0 or 1
    int b = blockIdx.x + 64 * grp;
    int lj = lane & 31;
    int jj = (lj < Ln) ? lj : Ln - 1;                // clamp for safe loads
    int base = lane & 32;                            // shfl source base
    float trj[Ln];
    #pragma unroll
    for (int i = 0; i < Ln; ++i) trj[i] = trans[i * Ln + jj];
    float bcj = bc[jj];
    size_t ix0 = (size_t)b * Ln + jj;
    float alpha = start[jj] + pf[ix0] + pb[ix0] + bcj;
    size_t ix1 = (size_t)(1 * Bn + b) * Ln + jj;
    size_t ix2 = (size_t)(2 * Bn + b) * Ln + jj;
    float e1 = pf[ix1] + pb[ix1] + bcj;
    float e2 = pf[ix2] + pb[ix2] + bcj;
    int m1 = mask[b * Tn + 1];
    int m2 = mask[b * Tn + 2];
    for (int t = 1; t < Tn; ++t) {
        float s0 = __shfl(alpha, base + 0, 64) + trj[0];
        float s1 = __shfl(alpha, base + 1, 64) + trj[1];
        float s2 = __shfl(alpha, base + 2, 64) + trj[2];
        float s3 = __shfl(alpha, base + 3, 64) + trj[3];
        float s4 = __shfl(alpha, base + 4, 64) + trj[4];
        float s5 = __shfl(alpha, base + 5, 64) + trj[5];
        float s6 = __shfl(alpha, base + 6, 64) + trj[6];
        float s7 = __shfl(alpha, base + 7, 64) + trj[7];
        float s8 = __shfl(alpha, base + 8, 64) + trj[8];
        float mx = fmaxf(fmaxf(fmaxf(s0, s1), fmaxf(s2, s3)),
                         fmaxf(fmaxf(s4, s5), fmaxf(fmaxf(s6, s7), s8)));
        float sum = __expf(s0 - mx) + __expf(s1 - mx) + __expf(s2 - mx)
                  + __expf(s3 - mx) + __expf(s4 - mx) + __expf(s5 - mx)
                  + __expf(s6 - mx) + __expf(s7 - mx) + __expf(s8 - mx);
        float nxt = mx + __logf(sum) + e1;
        if (m1) alpha = nxt;
        e1 = e2; m1 = m2;
        int t2 = (t + 2 < Tn) ? t + 2 : Tn - 1;
        size_t ixn = (size_t)(t2 * Bn + b) * Ln + jj;
        e2 = pf[ixn] + pb[ixn] + bcj;
        m2 = mask[b * Tn + t2];
    }
    float s = (lj < Ln) ? alpha + endt[lj] : -1e30f;
    float mx = s;
    #pragma unroll
    for (int d = 16; d >= 1; d >>= 1) mx = fmaxf(mx, __shfl_xor(mx, d, 64));
    float sm = __expf(s - mx);
    #pragma unroll
    for (int d = 16; d >= 1; d >>= 1) sm += __shfl_xor(sm, d, 64);
    if (lj == 0) logZ[b] = mx + __logf(sm);
}

// ---- CRF numerator: gold-path score is a plain sum -> fully parallel over t ----
__global__ __launch_bounds__(64) void k_crf_num(
    const float* __restrict__ pf, const float* __restrict__ pb,
    const float* __restrict__ bc, const int* __restrict__ labels,
    const int* __restrict__ mask, const float* __restrict__ trans,
    const float* __restrict__ start, const float* __restrict__ endt,
    float* __restrict__ score) {
    int b = blockIdx.x, lane = threadIdx.x;
    float acc = 0.f; int cnt = 0;
    for (int t = lane; t < Tn; t += 64) {
        int tag = labels[b * Tn + t];
        int mt = mask[b * Tn + t];
        cnt += mt;
        size_t ix = (size_t)(t * Bn + b) * Ln + tag;
        float e = pf[ix] + pb[ix] + bc[tag];
        if (t == 0) {
            acc += start[tag] + e;
        } else {
            int prev = labels[b * Tn + t - 1];
            if (mt) acc += trans[prev * Ln + tag] + e;
        }
    }
    #pragma unroll
    for (int m = 32; m >= 1; m >>= 1) {
        acc += __shfl_xor(acc, m, 64);
        cnt += __shfl_xor(cnt, m, 64);
    }
    if (lane == 0) {
        int send = cnt - 1;
        int last = labels[b * Tn + send];
        score[b] = acc + endt[last];
    }
}

__global__ __launch_bounds__(128) void k_final(
    const float* __restrict__ score, const float* __restrict__ logZ,
    float* __restrict__ out) {
    __shared__ float s_s[128];
    int tid = threadIdx.x;
    s_s[tid] = score[tid] - logZ[tid];
    #pragma unroll
    for (int m = 64; m >= 1; m >>= 1) {
        __syncthreads();
        if (tid < m) s_s[tid] += s_s[tid + m];
    }
    if (tid == 0) out[0] = -s_s[0] / (float)Bn;
}

extern "C" void kernel_launch(void* const* d_in, const int* in_sizes, int n_in,
                              void* d_out, int out_size, void* d_ws, size_t ws_size,
                              hipStream_t stream) {
    const int* ids = (const int*)d_in[0];
    const int* msk = (const int*)d_in[1];
    const int* lbl = (const int*)d_in[2];
    const float* emb = (const float*)d_in[3];
    const float* Wih_f = (const float*)d_in[4];
    const float* Whh_f = (const float*)d_in[5];
    const float* b_f = (const float*)d_in[6];
    const float* Wih_b = (const float*)d_in[7];
    const float* Whh_b = (const float*)d_in[8];
    const float* b_b = (const float*)d_in[9];
    const float* Wc = (const float*)d_in[10];
    const float* bc = (const float*)d_in[11];
    const float* trans = (const float*)d_in[12];
    const float* st = (const float*)d_in[13];
    const float* en = (const float*)d_in[14];

    char* ws = (char*)d_ws;
    float* WihT_f = (float*)ws;                 ws += (size_t)En * Gn * 4;      // 1,228,800
    float* WihT_b = (float*)ws;                 ws += (size_t)En * Gn * 4;
    unsigned int* qr_f = (unsigned int*)ws;     ws += 65536;                    // 64 KB each
    unsigned int* ql_f = (unsigned int*)ws;     ws += 65536;
    unsigned int* qr_b = (unsigned int*)ws;     ws += 65536;
    unsigned int* ql_b = (unsigned int*)ws;     ws += 65536;
    float* scl_f = (float*)ws;                  ws += 4096;
    float* scl_b = (float*)ws;                  ws += 4096;
    unsigned short* Pf = (unsigned short*)ws;   ws += (size_t)Vn * Gn * 2;      // 20,480,000
    unsigned short* Pb = (unsigned short*)ws;   ws += (size_t)Vn * Gn * 2;
    float* em_pf = (float*)ws;                  ws += (size_t)Tn * Bn * Ln * 4; // 2,359,296
    float* em_pb = (float*)ws;                  ws += (size_t)Tn * Bn * Ln * 4;
    float* score = (float*)ws;                  ws += 512;
    float* logZ = (float*)ws;                   ws += 512;

    k_transpose_wih<<<dim3(1200, 2), 256, 0, stream>>>(Wih_f, Wih_b, WihT_f, WihT_b);
    k_quant_whh<<<dim3(1024, 2), 64, 0, stream>>>(Whh_f, Whh_b, qr_f, ql_f, qr_b, ql_b, scl_f, scl_b);
    k_proj<<<dim3(313, 4, 2), 256, 0, stream>>>(emb, WihT_f, WihT_b, b_f, b_b, Pf, Pb);
    k_lstm<<<256, 1024, 0, stream>>>(ids,
        (const uint4*)qr_f, (const uint4*)ql_f, (const uint4*)qr_b, (const uint4*)ql_b,
        scl_f, scl_b, Pf, Pb, Wc, em_pf, em_pb);
    k_crf_den<<<64, 64, 0, stream>>>(em_pf, em_pb, bc, msk, trans, st, en, logZ);
    k_crf_num<<<128, 64, 0, stream>>>(em_pf, em_pb, bc, lbl, msk, trans, st, en, score);
    k_final<<<1, 128, 0, stream>>>(score, logZ, (float*)d_out);
}

// Round 9
// 929.327 us; speedup vs baseline: 1.7755x; 1.1772x over previous
//
#include <hip/hip_runtime.h>
#include <hip/hip_bf16.h>
#include <hip/hip_fp16.h>

#define Vn 10000
#define En 300
#define E2n 150   // En/2 f16 pairs
#define Hn 256
#define Gn 1024   // 4*H
#define Ln 9
#define Bn 128
#define Tn 512

#if defined(__has_builtin)
#  if __has_builtin(__builtin_amdgcn_sdot8)
#    define HAS_SDOT8 1
#  endif
#  if __has_builtin(__builtin_amdgcn_fdot2)
#    define HAS_FDOT2 1
#  endif
#endif
#ifndef HAS_SDOT8
#  define HAS_SDOT8 0
#endif
#ifndef HAS_FDOT2
#  define HAS_FDOT2 0
#endif

typedef _Float16 half2_t __attribute__((ext_vector_type(2)));

static __device__ __forceinline__ float bf2f(unsigned short u) {
    return __uint_as_float(((unsigned int)u) << 16);
}
static __device__ __forceinline__ unsigned short f2bf(float f) {
    unsigned int x = __float_as_uint(f);
    return (unsigned short)((x + 0x7FFFu + ((x >> 16) & 1u)) >> 16);
}
static __device__ __forceinline__ float sigm(float x) {
    return 1.f / (1.f + __expf(-x));
}
static __device__ __forceinline__ float tanh_fast(float x) {
    return 2.f / (1.f + __expf(-2.f * x)) - 1.f;
}
// i4x8 dot: both operands are 8 packed signed nibbles
static __device__ __forceinline__ int dot8(unsigned int w, int h, int acc) {
#if HAS_SDOT8
    return __builtin_amdgcn_sdot8((int)w, h, acc, false);
#else
    unsigned int wl = ((w & 0x0F0F0F0Fu) ^ 0x08080808u) - 0x08080808u;
    unsigned int wh = (((w >> 4) & 0x0F0F0F0Fu) ^ 0x08080808u) - 0x08080808u;
    unsigned int hl = (((unsigned)h & 0x0F0F0F0Fu) ^ 0x08080808u) - 0x08080808u;
    unsigned int hh = ((((unsigned)h >> 4) & 0x0F0F0F0Fu) ^ 0x08080808u) - 0x08080808u;
    acc = __builtin_amdgcn_sdot4((int)wl, (int)hl, acc, false);
    return __builtin_amdgcn_sdot4((int)wh, (int)hh, acc, false);
#endif
}
static __device__ __forceinline__ float fdot2f(unsigned int a, unsigned int b, float acc) {
#if HAS_FDOT2
    return __builtin_amdgcn_fdot2(__builtin_bit_cast(half2_t, a),
                                  __builtin_bit_cast(half2_t, b), acc, false);
#else
    half2_t av = __builtin_bit_cast(half2_t, a);
    half2_t bv = __builtin_bit_cast(half2_t, b);
    return acc + (float)av.x * (float)bv.x + (float)av.y * (float)bv.y;
#endif
}
static __device__ __forceinline__ unsigned int packf16(float a, float b) {
    half2_t v = {(_Float16)a, (_Float16)b};
    return __builtin_bit_cast(unsigned int, v);
}

// ---- pack emb (10000,300) f32 -> f16-pair dwords [v][e2] ----
__global__ __launch_bounds__(256) void k_prep_emb(
    const float* __restrict__ emb, unsigned int* __restrict__ embp) {
    int n = blockIdx.x * 256 + threadIdx.x;
    if (n >= Vn * E2n) return;
    int v = n / E2n, e2 = n % E2n;
    float a = emb[(size_t)v * En + 2 * e2];
    float b = emb[(size_t)v * En + 2 * e2 + 1];
    embp[n] = packf16(a, b);
}

// ---- pack+transpose Wih (1024,300) -> WT16 [e2][j] f16-pair dwords ----
__global__ __launch_bounds__(256) void k_prep_wt(
    const float* __restrict__ Wf, const float* __restrict__ Wb,
    unsigned int* __restrict__ Tf, unsigned int* __restrict__ Tb) {
    int n = blockIdx.x * 256 + threadIdx.x;           // < 153600
    const float* src = blockIdx.y ? Wb : Wf;
    unsigned int* dst = blockIdx.y ? Tb : Tf;
    int e2 = n / Gn, j = n % Gn;
    float a = src[(size_t)j * En + 2 * e2];
    float b = src[(size_t)j * En + 2 * e2 + 1];
    dst[n] = packf16(a, b);
}

// ---- quantize Whh (1024,256) f32 -> i4 nibbles, per-gate-row scale ----
// dwords e=0..15 (k=0..127) -> qr (register half); e=16..31 -> ql (LDS half);
// both as uint4 tiles [e>>2][1024]. gate = scl[j]*dotsum + P, scl = rowmax/49.
__global__ __launch_bounds__(64) void k_quant_whh(
    const float* __restrict__ Wf, const float* __restrict__ Wb,
    unsigned int* __restrict__ qr_f, unsigned int* __restrict__ ql_f,
    unsigned int* __restrict__ qr_b, unsigned int* __restrict__ ql_b,
    float* __restrict__ scl_f, float* __restrict__ scl_b) {
    int j = blockIdx.x;                 // 0..1023 (gate-row)
    int dir = blockIdx.y;
    int lane = threadIdx.x;             // lanes 0..31 = dword index e
    const float* W = dir ? Wb : Wf;
    float w8[8];
    float m = 0.f;
    if (lane < 32) {
        float4 wlo = *(const float4*)&W[(size_t)j * Hn + 8 * lane];
        float4 whi = *(const float4*)&W[(size_t)j * Hn + 8 * lane + 4];
        w8[0] = wlo.x; w8[1] = wlo.y; w8[2] = wlo.z; w8[3] = wlo.w;
        w8[4] = whi.x; w8[5] = whi.y; w8[6] = whi.z; w8[7] = whi.w;
        #pragma unroll
        for (int i = 0; i < 8; ++i) m = fmaxf(m, fabsf(w8[i]));
    }
    #pragma unroll
    for (int sft = 32; sft >= 1; sft >>= 1) m = fmaxf(m, __shfl_xor(m, sft, 64));
    float inv = (m > 0.f) ? (7.f / m) : 0.f;
    if (lane < 32) {
        unsigned int d = 0;
        #pragma unroll
        for (int i = 0; i < 8; ++i) {
            int qi = (int)rintf(w8[i] * inv);
            d |= ((unsigned int)(qi & 0xF)) << (4 * i);
        }
        if (lane < 16)
            (dir ? qr_b : qr_f)[(size_t)((lane >> 2) * 1024 + j) * 4 + (lane & 3)] = d;
        else {
            int e = lane - 16;
            (dir ? ql_b : ql_f)[(size_t)((e >> 2) * 1024 + j) * 4 + (e & 3)] = d;
        }
    }
    if (lane == 0) (dir ? scl_b : scl_f)[j] = m / 49.f;
}

// ---- P = emb @ WihT + b via v_dot2_f32_f16 : (10000, 1024) bf16 per dir ----
__global__ __launch_bounds__(256) void k_proj(
    const unsigned int* __restrict__ embp,
    const unsigned int* __restrict__ WT16_f, const unsigned int* __restrict__ WT16_b,
    const float* __restrict__ b_f, const float* __restrict__ b_b,
    unsigned short* __restrict__ Pf, unsigned short* __restrict__ Pb) {
    int tid = threadIdx.x;
    int tx = tid & 63, ty = tid >> 6;
    int dir = blockIdx.z;
    const unsigned int* WT = dir ? WT16_b : WT16_f;
    const float* bias = dir ? b_b : b_f;
    unsigned short* P = dir ? Pb : Pf;
    int v0 = blockIdx.x * 32 + ty * 8;               // 313 blocks, tail-guarded
    int j0 = blockIdx.y * 256 + tx * 4;
    int vr[8];
    #pragma unroll
    for (int r = 0; r < 8; ++r) { int v = v0 + r; vr[r] = (v < Vn) ? v : Vn - 1; }
    float4 acc[8];
    #pragma unroll
    for (int r = 0; r < 8; ++r) acc[r] = make_float4(0.f, 0.f, 0.f, 0.f);
    for (int e2 = 0; e2 < E2n; ++e2) {
        uint4 w = *(const uint4*)&WT[(size_t)e2 * Gn + j0];
        #pragma unroll
        for (int r = 0; r < 8; ++r) {
            unsigned int a = embp[(size_t)vr[r] * E2n + e2];
            acc[r].x = fdot2f(a, w.x, acc[r].x);
            acc[r].y = fdot2f(a, w.y, acc[r].y);
            acc[r].z = fdot2f(a, w.z, acc[r].z);
            acc[r].w = fdot2f(a, w.w, acc[r].w);
        }
    }
    float4 bb = *(const float4*)&bias[j0];
    #pragma unroll
    for (int r = 0; r < 8; ++r) {
        if (v0 + r < Vn) {
            ushort4 o;
            o.x = f2bf(acc[r].x + bb.x); o.y = f2bf(acc[r].y + bb.y);
            o.z = f2bf(acc[r].z + bb.z); o.w = f2bf(acc[r].w + bb.w);
            *(ushort4*)&P[(size_t)(v0 + r) * Gn + j0] = o;
        }
    }
}

// ---- persistent BiLSTM recurrence: 256 WGs = 2 dir x 128 batch, 1024 thr ----
// r8 core (16 i4-dwords pinned + 16 in LDS, readlane->dot8) with: emission
// REMOVED (separate k_emit; bf16 h written to global), 4 accumulator chains
// (kills the 2-chain dot-latency stall), single combined pin asm.
__global__ __launch_bounds__(1024, 4) void k_lstm(
    const int* __restrict__ ids,
    const uint4* __restrict__ qr_f, const uint4* __restrict__ ql_f,
    const uint4* __restrict__ qr_b, const uint4* __restrict__ ql_b,
    const float* __restrict__ scl_f, const float* __restrict__ scl_b,
    const unsigned short* __restrict__ Pf, const unsigned short* __restrict__ Pb,
    unsigned short* __restrict__ hs_f, unsigned short* __restrict__ hs_b) {
    __shared__ uint4 wlds[4 * 1024];         // 64 KB streamed weight half (k=128..255)
    __shared__ float g_stage[Gn];            // 4 KB gate preacts
    __shared__ uint4 h4v[8];                 // 128 B i4 h (dword D = units 8D..8D+7)
    __shared__ int ids_lds[Tn];              // 2 KB
    int tid = threadIdx.x;
    int dir = blockIdx.x >> 7;
    int batch = blockIdx.x & 127;
    const uint4* qr = dir ? qr_b : qr_f;
    const uint4* ql = dir ? ql_b : ql_f;
    const unsigned short* P = dir ? Pb : Pf;
    unsigned short* hs = dir ? hs_b : hs_f;

    unsigned int wReg[16];
    #pragma unroll
    for (int d4 = 0; d4 < 4; ++d4) {
        uint4 v = qr[(size_t)d4 * 1024 + tid];
        wReg[4*d4+0] = v.x; wReg[4*d4+1] = v.y; wReg[4*d4+2] = v.z; wReg[4*d4+3] = v.w;
        wlds[d4 * 1024 + tid] = ql[(size_t)d4 * 1024 + tid];
    }
    float sc = (dir ? scl_b : scl_f)[tid];
    if (tid < Tn) ids_lds[tid] = ids[batch * Tn + tid];
    if (tid < 8) { uint4 z = {0u, 0u, 0u, 0u}; h4v[tid] = z; }
    float c = 0.f;
    __syncthreads();

    int t0 = dir ? (Tn - 1) : 0;
    float p = bf2f(P[(size_t)ids_lds[t0] * Gn + tid]);

    for (int s = 0; s < Tn; ++s) {
        // loop-carried pin (single statement): wReg must stay live in VGPRs
        asm volatile("" : "+v"(wReg[0]), "+v"(wReg[1]), "+v"(wReg[2]), "+v"(wReg[3]),
                          "+v"(wReg[4]), "+v"(wReg[5]), "+v"(wReg[6]), "+v"(wReg[7]),
                          "+v"(wReg[8]), "+v"(wReg[9]), "+v"(wReg[10]), "+v"(wReg[11]),
                          "+v"(wReg[12]), "+v"(wReg[13]), "+v"(wReg[14]), "+v"(wReg[15]));

        int t = dir ? (Tn - 1 - s) : s;
        int s2 = (s + 1 < Tn) ? s + 1 : Tn - 1;
        int t2 = dir ? (Tn - 1 - s2) : s2;
        unsigned short nx = P[(size_t)ids_lds[t2] * Gn + tid];   // next-step prefetch

        uint4 hq  = h4v[tid & 7];                     // 1 ds_read_b128
        uint4 wv0 = wlds[tid];                        // 4 ds_read_b128 (k=128..255)
        uint4 wv1 = wlds[1024 + tid];
        uint4 wv2 = wlds[2048 + tid];
        uint4 wv3 = wlds[3072 + tid];

        int a0 = 0, a1 = 0, a2 = 0, a3 = 0;           // 4 independent chains
        #pragma unroll
        for (int g = 0; g < 4; ++g) {                 // register half: h dwords 0..15
            int h0 = __builtin_amdgcn_readlane((int)hq.x, g);
            int h1 = __builtin_amdgcn_readlane((int)hq.y, g);
            int h2 = __builtin_amdgcn_readlane((int)hq.z, g);
            int h3 = __builtin_amdgcn_readlane((int)hq.w, g);
            a0 = dot8(wReg[4*g+0], h0, a0);
            a1 = dot8(wReg[4*g+1], h1, a1);
            a2 = dot8(wReg[4*g+2], h2, a2);
            a3 = dot8(wReg[4*g+3], h3, a3);
        }
        {                                             // LDS half: h dwords 16..31
            uint4 wv[4] = {wv0, wv1, wv2, wv3};
            #pragma unroll
            for (int g = 4; g < 8; ++g) {
                int h0 = __builtin_amdgcn_readlane((int)hq.x, g);
                int h1 = __builtin_amdgcn_readlane((int)hq.y, g);
                int h2 = __builtin_amdgcn_readlane((int)hq.z, g);
                int h3 = __builtin_amdgcn_readlane((int)hq.w, g);
                a0 = dot8(wv[g-4].x, h0, a0);
                a1 = dot8(wv[g-4].y, h1, a1);
                a2 = dot8(wv[g-4].z, h2, a2);
                a3 = dot8(wv[g-4].w, h3, a3);
            }
        }
        g_stage[tid] = sc * (float)((a0 + a1) + (a2 + a3)) + p;
        __syncthreads();                              // B1: gates ready
        if (tid < Hn) {
            float gi = g_stage[tid];
            float gf = g_stage[tid + 256];
            float gg = g_stage[tid + 512];
            float go = g_stage[tid + 768];
            float cn = sigm(gf) * c + sigm(gi) * tanh_fast(gg);
            float hn = sigm(go) * tanh_fast(cn);
            c = cn;
            hs[(size_t)(t * Bn + batch) * Hn + tid] = f2bf(hn);
            int qh = (int)rintf(7.f * hn);            // in [-7,7]
            int qo = __shfl_xor(qh, 1, 64);           // partner unit, same wave
            if ((tid & 1) == 0)
                ((char*)h4v)[tid >> 1] = (char)((qh & 0xF) | ((qo & 0xF) << 4));
        }
        __syncthreads();                              // B2: new h visible
        p = bf2f(nx);
    }
}

// ---- emissions: em[t,b,l] = [hf|hb].Wc[l] + bc[l], one wave per token ----
__global__ __launch_bounds__(256) void k_emit(
    const unsigned short* __restrict__ hs_f, const unsigned short* __restrict__ hs_b,
    const float* __restrict__ Wc, const float* __restrict__ bc,
    float* __restrict__ em) {
    __shared__ float wc_s[Ln * 2 * Hn];
    int tid = threadIdx.x;
    for (int i = tid; i < Ln * 2 * Hn; i += 256) wc_s[i] = Wc[i];
    __syncthreads();
    int lane = tid & 63, wid = tid >> 6;
    int tb = blockIdx.x * 4 + wid;                   // t*128 + b, < 65536
    const unsigned short* hf = hs_f + (size_t)tb * Hn;
    const unsigned short* hb = hs_b + (size_t)tb * Hn;
    uint2 uf = *(const uint2*)&hf[lane * 4];
    uint2 ub = *(const uint2*)&hb[lane * 4];
    float f0 = __uint_as_float(uf.x << 16), f1 = __uint_as_float(uf.x & 0xFFFF0000u);
    float f2v = __uint_as_float(uf.y << 16), f3 = __uint_as_float(uf.y & 0xFFFF0000u);
    float b0 = __uint_as_float(ub.x << 16), b1 = __uint_as_float(ub.x & 0xFFFF0000u);
    float b2 = __uint_as_float(ub.y << 16), b3 = __uint_as_float(ub.y & 0xFFFF0000u);
    #pragma unroll
    for (int l = 0; l < Ln; ++l) {
        const float* w = &wc_s[l * 2 * Hn];
        float p = f0 * w[4 * lane] + f1 * w[4 * lane + 1]
                + f2v * w[4 * lane + 2] + f3 * w[4 * lane + 3]
                + b0 * w[Hn + 4 * lane] + b1 * w[Hn + 4 * lane + 1]
                + b2 * w[Hn + 4 * lane + 2] + b3 * w[Hn + 4 * lane + 3];
        #pragma unroll
        for (int m = 32; m >= 1; m >>= 1) p += __shfl_xor(p, m, 64);
        if (lane == 0) em[(size_t)tb * Ln + l] = p + bc[l];
    }
}

// ---- CRF denominator: 64 single-wave WGs, 2 batches/wave, shuffle-based ----
__global__ __launch_bounds__(64) void k_crf_den(
    const float* __restrict__ em, const int* __restrict__ mask,
    const float* __restrict__ trans, const float* __restrict__ start,
    const float* __restrict__ endt, float* __restrict__ logZ) {
    int lane = threadIdx.x;
    int grp = lane >> 5;                             // 0 or 1
    int b = blockIdx.x + 64 * grp;
    int lj = lane & 31;
    int jj = (lj < Ln) ? lj : Ln - 1;                // clamp for safe loads
    int base = lane & 32;                            // shfl source base
    float trj[Ln];
    #pragma unroll
    for (int i = 0; i < Ln; ++i) trj[i] = trans[i * Ln + jj];
    float alpha = start[jj] + em[(size_t)b * Ln + jj];
    float e1 = em[(size_t)(1 * Bn + b) * Ln + jj];
    float e2 = em[(size_t)(2 * Bn + b) * Ln + jj];
    int m1 = mask[b * Tn + 1];
    int m2 = mask[b * Tn + 2];
    for (int t = 1; t < Tn; ++t) {
        float s0 = __shfl(alpha, base + 0, 64) + trj[0];
        float s1 = __shfl(alpha, base + 1, 64) + trj[1];
        float s2 = __shfl(alpha, base + 2, 64) + trj[2];
        float s3 = __shfl(alpha, base + 3, 64) + trj[3];
        float s4 = __shfl(alpha, base + 4, 64) + trj[4];
        float s5 = __shfl(alpha, base + 5, 64) + trj[5];
        float s6 = __shfl(alpha, base + 6, 64) + trj[6];
        float s7 = __shfl(alpha, base + 7, 64) + trj[7];
        float s8 = __shfl(alpha, base + 8, 64) + trj[8];
        float mx = fmaxf(fmaxf(fmaxf(s0, s1), fmaxf(s2, s3)),
                         fmaxf(fmaxf(s4, s5), fmaxf(fmaxf(s6, s7), s8)));
        float sum = __expf(s0 - mx) + __expf(s1 - mx) + __expf(s2 - mx)
                  + __expf(s3 - mx) + __expf(s4 - mx) + __expf(s5 - mx)
                  + __expf(s6 - mx) + __expf(s7 - mx) + __expf(s8 - mx);
        float nxt = mx + __logf(sum) + e1;
        if (m1) alpha = nxt;
        e1 = e2; m1 = m2;
        int t2 = (t + 2 < Tn) ? t + 2 : Tn - 1;
        e2 = em[(size_t)(t2 * Bn + b) * Ln + jj];
        m2 = mask[b * Tn + t2];
    }
    float s = (lj < Ln) ? alpha + endt[lj] : -1e30f;
    float mx = s;
    #pragma unroll
    for (int d = 16; d >= 1; d >>= 1) mx = fmaxf(mx, __shfl_xor(mx, d, 64));
    float sm = __expf(s - mx);
    #pragma unroll
    for (int d = 16; d >= 1; d >>= 1) sm += __shfl_xor(sm, d, 64);
    if (lj == 0) logZ[b] = mx + __logf(sm);
}

// ---- CRF numerator: gold-path score is a plain sum -> fully parallel over t ----
__global__ __launch_bounds__(64) void k_crf_num(
    const float* __restrict__ em, const int* __restrict__ labels,
    const int* __restrict__ mask, const float* __restrict__ trans,
    const float* __restrict__ start, const float* __restrict__ endt,
    float* __restrict__ score) {
    int b = blockIdx.x, lane = threadIdx.x;
    float acc = 0.f; int cnt = 0;
    for (int t = lane; t < Tn; t += 64) {
        int tag = labels[b * Tn + t];
        int mt = mask[b * Tn + t];
        cnt += mt;
        float e = em[(size_t)(t * Bn + b) * Ln + tag];
        if (t == 0) {
            acc += start[tag] + e;
        } else {
            int prev = labels[b * Tn + t - 1];
            if (mt) acc += trans[prev * Ln + tag] + e;
        }
    }
    #pragma unroll
    for (int m = 32; m >= 1; m >>= 1) {
        acc += __shfl_xor(acc, m, 64);
        cnt += __shfl_xor(cnt, m, 64);
    }
    if (lane == 0) {
        int send = cnt - 1;
        int last = labels[b * Tn + send];
        score[b] = acc + endt[last];
    }
}

__global__ __launch_bounds__(128) void k_final(
    const float* __restrict__ score, const float* __restrict__ logZ,
    float* __restrict__ out) {
    __shared__ float s_s[128];
    int tid = threadIdx.x;
    s_s[tid] = score[tid] - logZ[tid];
    #pragma unroll
    for (int m = 64; m >= 1; m >>= 1) {
        __syncthreads();
        if (tid < m) s_s[tid] += s_s[tid + m];
    }
    if (tid == 0) out[0] = -s_s[0] / (float)Bn;
}

extern "C" void kernel_launch(void* const* d_in, const int* in_sizes, int n_in,
                              void* d_out, int out_size, void* d_ws, size_t ws_size,
                              hipStream_t stream) {
    const int* ids = (const int*)d_in[0];
    const int* msk = (const int*)d_in[1];
    const int* lbl = (const int*)d_in[2];
    const float* emb = (const float*)d_in[3];
    const float* Wih_f = (const float*)d_in[4];
    const float* Whh_f = (const float*)d_in[5];
    const float* b_f = (const float*)d_in[6];
    const float* Wih_b = (const float*)d_in[7];
    const float* Whh_b = (const float*)d_in[8];
    const float* b_b = (const float*)d_in[9];
    const float* Wc = (const float*)d_in[10];
    const float* bc = (const float*)d_in[11];
    const float* trans = (const float*)d_in[12];
    const float* st = (const float*)d_in[13];
    const float* en = (const float*)d_in[14];

    char* ws = (char*)d_ws;
    unsigned int* WT16_f = (unsigned int*)ws;   ws += (size_t)E2n * Gn * 4;     // 614,400
    unsigned int* WT16_b = (unsigned int*)ws;   ws += (size_t)E2n * Gn * 4;
    unsigned int* qr_f = (unsigned int*)ws;     ws += 65536;                    // 64 KB each
    unsigned int* ql_f = (unsigned int*)ws;     ws += 65536;
    unsigned int* qr_b = (unsigned int*)ws;     ws += 65536;
    unsigned int* ql_b = (unsigned int*)ws;     ws += 65536;
    float* scl_f = (float*)ws;                  ws += 4096;
    float* scl_b = (float*)ws;                  ws += 4096;
    unsigned short* Pf = (unsigned short*)ws;   ws += (size_t)Vn * Gn * 2;      // 20,480,000
    unsigned short* Pb = (unsigned short*)ws;   ws += (size_t)Vn * Gn * 2;
    unsigned short* hs_f = (unsigned short*)ws; ws += (size_t)Tn * Bn * Hn * 2; // 33,554,432
    unsigned short* hs_b = (unsigned short*)ws; ws += (size_t)Tn * Bn * Hn * 2;
    float* em = (float*)ws;                     ws += (size_t)Tn * Bn * Ln * 4; // 2,359,296
    float* score = (float*)ws;                  ws += 512;
    float* logZ = (float*)ws;                   ws += 512;
    // embp (6 MB) aliases hs_f: written by k_prep_emb, read by k_proj, dead
    // before k_lstm overwrites hs_f. Re-generated every graph replay.
    unsigned int* embp = (unsigned int*)hs_f;

    k_prep_emb<<<(Vn * E2n + 255) / 256, 256, 0, stream>>>(emb, embp);
    k_prep_wt<<<dim3((E2n * Gn) / 256, 2), 256, 0, stream>>>(Wih_f, Wih_b, WT16_f, WT16_b);
    k_quant_whh<<<dim3(1024, 2), 64, 0, stream>>>(Whh_f, Whh_b, qr_f, ql_f, qr_b, ql_b, scl_f, scl_b);
    k_proj<<<dim3(313, 4, 2), 256, 0, stream>>>(embp, WT16_f, WT16_b, b_f, b_b, Pf, Pb);
    k_lstm<<<256, 1024, 0, stream>>>(ids,
        (const uint4*)qr_f, (const uint4*)ql_f, (const uint4*)qr_b, (const uint4*)ql_b,
        scl_f, scl_b, Pf, Pb, hs_f, hs_b);
    k_emit<<<16384, 256, 0, stream>>>(hs_f, hs_b, Wc, bc, em);
    k_crf_den<<<64, 64, 0, stream>>>(em, msk, trans, st, en, logZ);
    k_crf_num<<<128, 64, 0, stream>>>(em, lbl, msk, trans, st, en, score);
    k_final<<<1, 128, 0, stream>>>(score, logZ, (float*)d_out);
}